// Round 5
// baseline (563.831 us; speedup 1.0000x reference)
//
#include <hip/hip_runtime.h>

#define S_LEN 4096
#define D_MODEL 1024
#define NHEAD 16
#define DK 64
#define HID 2730
#define HIDP 2816
#define QKV_LD 3072

typedef unsigned short u16;
typedef unsigned int u32;
typedef __bf16 bf16x8 __attribute__((ext_vector_type(8)));
typedef float f32x4 __attribute__((ext_vector_type(4)));

#define MFMA16 __builtin_amdgcn_mfma_f32_16x16x32_bf16

__device__ __forceinline__ float b2f(u16 u) {
    return __builtin_bit_cast(float, (u32)u << 16);
}
__device__ __forceinline__ u16 f2b(float f) {
    u32 u = __builtin_bit_cast(u32, f);
    u += 0x7FFF + ((u >> 16) & 1);
    return (u16)(u >> 16);
}
// async global->LDS, 16B per lane; dest = lds base (wave-uniform) + lane*16
__device__ __forceinline__ void gll16(const u16* g, u16* l) {
    __builtin_amdgcn_global_load_lds(
        (__attribute__((address_space(1))) void*)(g),
        (__attribute__((address_space(3))) void*)(l),
        16, 0, 0);
}

// ---------------------------------------------------------------------------
// RMSNorm: one block per row (D=1024), fp32 in -> bf16 out
// ---------------------------------------------------------------------------
__global__ __launch_bounds__(256)
void rmsnorm_k(const float* __restrict__ x, const float* __restrict__ w,
               u16* __restrict__ out) {
    const int row = blockIdx.x;
    const int tid = threadIdx.x;
    const float4 v = ((const float4*)(x + (size_t)row * D_MODEL))[tid];
    float ss = v.x * v.x + v.y * v.y + v.z * v.z + v.w * v.w;
    for (int o = 32; o; o >>= 1) ss += __shfl_down(ss, o);
    __shared__ float red[4];
    if ((tid & 63) == 0) red[tid >> 6] = ss;
    __syncthreads();
    const float tot = red[0] + red[1] + red[2] + red[3];
    const float rs = rsqrtf(tot * (1.0f / D_MODEL) + 1e-6f);
    const float4 wv = ((const float4*)w)[tid];
    u16* op = out + (size_t)row * D_MODEL + tid * 4;
    u32 p0 = (u32)f2b(v.x * rs * wv.x) | ((u32)f2b(v.y * rs * wv.y) << 16);
    u32 p1 = (u32)f2b(v.z * rs * wv.z) | ((u32)f2b(v.w * rs * wv.w) << 16);
    uint2 pk; pk.x = p0; pk.y = p1;
    *(uint2*)op = pk;
}

// ---------------------------------------------------------------------------
// Tiled transpose + cast fp32 -> bf16.  out[r][c] = in[c][r], zero-padded.
// ---------------------------------------------------------------------------
__global__ __launch_bounds__(256)
void tcast_k(const float* __restrict__ in, int R, int C,
             u16* __restrict__ out, int outC) {
    __shared__ float t[32][33];
    const int r0 = blockIdx.y * 32;
    const int c0 = blockIdx.x * 32;
    const int tx = threadIdx.x, ty = threadIdx.y;
#pragma unroll
    for (int j = 0; j < 4; ++j) {
        int ir = c0 + ty + j * 8;
        int ic = r0 + tx;
        t[ty + j * 8][tx] = (ir < R && ic < C) ? in[(size_t)ir * C + ic] : 0.0f;
    }
    __syncthreads();
#pragma unroll
    for (int j = 0; j < 4; ++j)
        out[(size_t)(r0 + ty + j * 8) * outC + c0 + tx] = f2b(t[tx][ty + j * 8]);
}

// ---------------------------------------------------------------------------
// Pack K/V per head: kp[h][s][d] = qkv[s][1024 + h*64 + d]   (copy)
//                    vt[h][d][s] = qkv[s][2048 + h*64 + d]   (transpose)
// grid: (S/32, DK/32, H), block (32,8)
// ---------------------------------------------------------------------------
__global__ __launch_bounds__(256)
void packkv_k(const u16* __restrict__ qkv, u16* __restrict__ vt,
              u16* __restrict__ kp) {
    __shared__ u16 t[32][33];
    const int h = blockIdx.z;
    const int t0 = blockIdx.x * 32;
    const int d0 = blockIdx.y * 32;
    const int tx = threadIdx.x, ty = threadIdx.y;
#pragma unroll
    for (int j = 0; j < 4; ++j) {
        const int s = t0 + ty + j * 8;
        t[ty + j * 8][tx] = qkv[(size_t)s * QKV_LD + 2 * D_MODEL + h * DK + d0 + tx];
        kp[((size_t)h * S_LEN + s) * DK + d0 + tx] =
            qkv[(size_t)s * QKV_LD + D_MODEL + h * DK + d0 + tx];
    }
    __syncthreads();
#pragma unroll
    for (int j = 0; j < 4; ++j)
        vt[(size_t)h * DK * S_LEN + (size_t)(d0 + ty + j * 8) * S_LEN + t0 + tx] =
            t[tx][ty + j * 8];
}

// ---------------------------------------------------------------------------
// RoPE in place on Q and K halves of qkv buffer (row stride 3072)
// ---------------------------------------------------------------------------
__global__ __launch_bounds__(256)
void rope_k(u16* __restrict__ qkv, const float* __restrict__ fc,
            const float* __restrict__ fs) {
    const int idx = blockIdx.x * 256 + threadIdx.x;   // S*H*32 total
    const int s = idx >> 9;
    const int rem = idx & 511;
    const int h = rem >> 5;
    const int i = rem & 31;
    const size_t base = (size_t)s * QKV_LD + h * DK + 2 * i;
    const float c = fc[s * 32 + i], sn = fs[s * 32 + i];
    u16* q = qkv + base;
    u16* k = qkv + base + D_MODEL;
    float t0 = b2f(q[0]), t1 = b2f(q[1]);
    q[0] = f2b(t0 * c - t1 * sn);
    q[1] = f2b(t0 * sn + t1 * c);
    t0 = b2f(k[0]); t1 = b2f(k[1]);
    k[0] = f2b(t0 * c - t1 * sn);
    k[1] = f2b(t0 * sn + t1 * c);
}

// ---------------------------------------------------------------------------
// 128x128 GEMM (m97 structure): C = A @ Bt^T, global_load_lds staging.
// ---------------------------------------------------------------------------
template <int EPI>
__global__ __launch_bounds__(256)
void gemm128(const u16* __restrict__ A, int lda, const u16* __restrict__ Bt, int ldb,
             void* __restrict__ C, int ldc, int K, const float* __restrict__ resid) {
    const int m0 = blockIdx.y * 128, n0 = blockIdx.x * 128;
    const int tid = threadIdx.x;
    const int wave = tid >> 6, lane = tid & 63;
    const int wr = wave >> 1, wc = wave & 1;
    const int r16 = lane & 15, kq = lane >> 4;

    __shared__ __align__(16) u16 As[128 * 32];
    __shared__ __align__(16) u16 Bs[128 * 32];

    const int srow = tid >> 2, sk = (tid & 3) * 8;
    const u16* ag0 = A + (size_t)(m0 + srow) * lda + sk;
    const u16* ag1 = A + (size_t)(m0 + 64 + srow) * lda + sk;
    const u16* bg0 = Bt + (size_t)(n0 + srow) * ldb + sk;
    const u16* bg1 = Bt + (size_t)(n0 + 64 + srow) * ldb + sk;
    u16* asw = As + wave * 512;
    u16* bsw = Bs + wave * 512;

    f32x4 acc[16];
#pragma unroll
    for (int i = 0; i < 16; ++i) acc[i] = f32x4{0.f, 0.f, 0.f, 0.f};

    for (int k0 = 0; k0 < K; k0 += 32) {
        __syncthreads();
        gll16(ag0 + k0, asw);
        gll16(ag1 + k0, asw + 2048);
        gll16(bg0 + k0, bsw);
        gll16(bg1 + k0, bsw + 2048);
        __syncthreads();
        bf16x8 af[4], bf[4];
#pragma unroll
        for (int mt = 0; mt < 4; ++mt)
            af[mt] = *(const bf16x8*)&As[(wr * 64 + mt * 16 + r16) * 32 + kq * 8];
#pragma unroll
        for (int nt = 0; nt < 4; ++nt)
            bf[nt] = *(const bf16x8*)&Bs[(wc * 64 + nt * 16 + r16) * 32 + kq * 8];
#pragma unroll
        for (int mt = 0; mt < 4; ++mt)
#pragma unroll
            for (int nt = 0; nt < 4; ++nt)
                acc[mt * 4 + nt] = MFMA16(af[mt], bf[nt], acc[mt * 4 + nt], 0, 0, 0);
    }

#pragma unroll
    for (int mt = 0; mt < 4; ++mt) {
#pragma unroll
        for (int nt = 0; nt < 4; ++nt) {
            const int col = n0 + wc * 64 + nt * 16 + r16;
#pragma unroll
            for (int j = 0; j < 4; ++j) {
                const int row = m0 + wr * 64 + mt * 16 + kq * 4 + j;
                if (EPI == 0) {
                    ((u16*)C)[(size_t)row * ldc + col] = f2b(acc[mt * 4 + nt][j]);
                } else {
                    ((float*)C)[(size_t)row * ldc + col] =
                        resid[(size_t)row * ldc + col] + acc[mt * 4 + nt][j];
                }
            }
        }
    }
}

// ---------------------------------------------------------------------------
// FFN dual GEMM: tile 128(M) x 64(N per matrix); ff = silu(A@B1^T)*(A@B3^T)
// ---------------------------------------------------------------------------
__global__ __launch_bounds__(256)
void gemm_dual64(const u16* __restrict__ A, int lda,
                 const u16* __restrict__ B1, const u16* __restrict__ B3, int ldb,
                 u16* __restrict__ C, int ldc, int K) {
    const int m0 = blockIdx.y * 128, n0 = blockIdx.x * 64;
    const int tid = threadIdx.x;
    const int wave = tid >> 6, lane = tid & 63;
    const int r16 = lane & 15, kq = lane >> 4;

    __shared__ __align__(16) u16 As[128 * 32];
    __shared__ __align__(16) u16 B1s[64 * 32];
    __shared__ __align__(16) u16 B3s[64 * 32];

    const int srow = tid >> 2, sk = (tid & 3) * 8;
    const u16* ag0 = A + (size_t)(m0 + srow) * lda + sk;
    const u16* ag1 = A + (size_t)(m0 + 64 + srow) * lda + sk;
    const u16* b1g = B1 + (size_t)(n0 + srow) * ldb + sk;
    const u16* b3g = B3 + (size_t)(n0 + srow) * ldb + sk;
    u16* asw = As + wave * 512;
    u16* b1w = B1s + wave * 512;
    u16* b3w = B3s + wave * 512;

    f32x4 acc1[8], acc3[8];
#pragma unroll
    for (int i = 0; i < 8; ++i) {
        acc1[i] = f32x4{0.f, 0.f, 0.f, 0.f};
        acc3[i] = f32x4{0.f, 0.f, 0.f, 0.f};
    }

    for (int k0 = 0; k0 < K; k0 += 32) {
        __syncthreads();
        gll16(ag0 + k0, asw);
        gll16(ag1 + k0, asw + 2048);
        gll16(b1g + k0, b1w);
        gll16(b3g + k0, b3w);
        __syncthreads();
        bf16x8 af[2], b1f[4], b3f[4];
#pragma unroll
        for (int mt = 0; mt < 2; ++mt)
            af[mt] = *(const bf16x8*)&As[(wave * 32 + mt * 16 + r16) * 32 + kq * 8];
#pragma unroll
        for (int nt = 0; nt < 4; ++nt) {
            b1f[nt] = *(const bf16x8*)&B1s[(nt * 16 + r16) * 32 + kq * 8];
            b3f[nt] = *(const bf16x8*)&B3s[(nt * 16 + r16) * 32 + kq * 8];
        }
#pragma unroll
        for (int mt = 0; mt < 2; ++mt)
#pragma unroll
            for (int nt = 0; nt < 4; ++nt) {
                acc1[mt * 4 + nt] = MFMA16(af[mt], b1f[nt], acc1[mt * 4 + nt], 0, 0, 0);
                acc3[mt * 4 + nt] = MFMA16(af[mt], b3f[nt], acc3[mt * 4 + nt], 0, 0, 0);
            }
    }

#pragma unroll
    for (int mt = 0; mt < 2; ++mt)
#pragma unroll
        for (int nt = 0; nt < 4; ++nt) {
            const int col = n0 + nt * 16 + r16;
#pragma unroll
            for (int j = 0; j < 4; ++j) {
                const int row = m0 + wave * 32 + mt * 16 + kq * 4 + j;
                const float v1 = acc1[mt * 4 + nt][j];
                const float v3 = acc3[mt * 4 + nt][j];
                const float sig = 1.0f / (1.0f + __expf(-v1));
                C[(size_t)row * ldc + col] = f2b(v1 * sig * v3);
            }
        }
}

// ---------------------------------------------------------------------------
// Flash attention, S^T formulation, exp2 softmax, K packed per head,
// XCD-swizzled (head tied to lin%8 residue), register prefetch of next tile.
// Block = (pair, head); q-tiles {pair, 63-pair} -> uniform 65 tile-iters.
// ---------------------------------------------------------------------------
__global__ __launch_bounds__(256)
void flash_k(const u16* __restrict__ qkv, const u16* __restrict__ vt,
             const u16* __restrict__ kp, u16* __restrict__ ctx) {
    const int lin = blockIdx.y * 32 + blockIdx.x;
    const int h = (lin & 7) | (((lin >> 3) & 1) << 3);   // XCD-resident heads
    const int pair = lin >> 4;                           // 0..31
    const int tid = threadIdx.x;
    const int wave = tid >> 6, lane = tid & 63;
    const int r16 = lane & 15, kq = lane >> 4;

    __shared__ __align__(16) u16 Ks[64][72];    // [kv row][dk]
    __shared__ __align__(16) u16 Vs[64][72];    // [dk][kv row]  (from vt)
    __shared__ __align__(16) u16 Ps[4][16][72]; // per-wave: [q][kv]

    const u16* kb = kp + (size_t)h * S_LEN * DK;
    const u16* vbase = vt + (size_t)h * DK * S_LEN;
    const int ldr = tid >> 3, ldc_ = (tid & 7) * 8;   // staging row/col
    const float SC = 0.125f * 1.44269504f;            // scale * log2(e)

    for (int half = 0; half < 2; ++half) {
        const int qi = half ? (63 - pair) : pair;
        const int q0 = qi * 64;

        const u16* qrow = qkv + (size_t)(q0 + wave * 16 + r16) * QKV_LD + h * DK;
        const bf16x8 qf0 = *(const bf16x8*)(qrow + kq * 8);
        const bf16x8 qf1 = *(const bf16x8*)(qrow + 32 + kq * 8);

        f32x4 o[4];
#pragma unroll
        for (int i = 0; i < 4; ++i) o[i] = f32x4{0.f, 0.f, 0.f, 0.f};
        float mrun = -1e30f, lrun = 0.f;

        // prefetch tile 0
        uint4 kpr[2], vpr[2];
#pragma unroll
        for (int i = 0; i < 2; ++i) {
            const int r = ldr + i * 32;
            kpr[i] = *(const uint4*)(kb + (size_t)r * DK + ldc_);
            vpr[i] = *(const uint4*)(vbase + (size_t)r * S_LEN + ldc_);
        }

        for (int t = 0; t <= qi; ++t) {
            __syncthreads();
#pragma unroll
            for (int i = 0; i < 2; ++i) {
                const int r = ldr + i * 32;
                *(uint4*)&Ks[r][ldc_] = kpr[i];
                *(uint4*)&Vs[r][ldc_] = vpr[i];
            }
            __syncthreads();
            if (t < qi) {   // prefetch next tile while computing this one
                const int t1 = (t + 1) * 64;
#pragma unroll
                for (int i = 0; i < 2; ++i) {
                    const int r = ldr + i * 32;
                    kpr[i] = *(const uint4*)(kb + (size_t)(t1 + r) * DK + ldc_);
                    vpr[i] = *(const uint4*)(vbase + (size_t)r * S_LEN + t1 + ldc_);
                }
            }

            // S^T[kv][q]: A = K rows, B = Q rows
            f32x4 s[4];
#pragma unroll
            for (int nt = 0; nt < 4; ++nt) {
                s[nt] = f32x4{0.f, 0.f, 0.f, 0.f};
                const bf16x8 k0 = *(const bf16x8*)&Ks[nt * 16 + r16][kq * 8];
                s[nt] = MFMA16(k0, qf0, s[nt], 0, 0, 0);
                const bf16x8 k1 = *(const bf16x8*)&Ks[nt * 16 + r16][32 + kq * 8];
                s[nt] = MFMA16(k1, qf1, s[nt], 0, 0, 0);
            }

            // per-lane softmax (exp2 space) for column q = r16
            float v[16];
#pragma unroll
            for (int nt = 0; nt < 4; ++nt)
#pragma unroll
                for (int j = 0; j < 4; ++j) v[nt * 4 + j] = s[nt][j] * SC;
            if (t == qi) {                       // uniform branch: diag mask
                const int qloc = wave * 16 + r16;
#pragma unroll
                for (int nt = 0; nt < 4; ++nt)
#pragma unroll
                    for (int j = 0; j < 4; ++j)
                        if ((nt * 16 + kq * 4 + j) > qloc) v[nt * 4 + j] = -1e9f;
            }
            float red[8];
#pragma unroll
            for (int i = 0; i < 8; ++i) red[i] = fmaxf(v[2 * i], v[2 * i + 1]);
#pragma unroll
            for (int w2 = 4; w2; w2 >>= 1)
#pragma unroll
                for (int i = 0; i < 8; ++i)
                    if (i < w2) red[i] = fmaxf(red[2 * i], red[2 * i + 1]);
            float lm = red[0];
            lm = fmaxf(lm, __shfl_xor(lm, 16));
            lm = fmaxf(lm, __shfl_xor(lm, 32));
            const float mnew = fmaxf(mrun, lm);
            const float alpha = exp2f(mrun - mnew);
            mrun = mnew;
#pragma unroll
            for (int i = 0; i < 16; ++i) v[i] = exp2f(v[i] - mnew);
#pragma unroll
            for (int i = 0; i < 8; ++i) red[i] = v[2 * i] + v[2 * i + 1];
#pragma unroll
            for (int w2 = 4; w2; w2 >>= 1)
#pragma unroll
                for (int i = 0; i < 8; ++i)
                    if (i < w2) red[i] = red[2 * i] + red[2 * i + 1];
            float rs = red[0];
            rs += __shfl_xor(rs, 16);
            rs += __shfl_xor(rs, 32);
            lrun = lrun * alpha + rs;
#pragma unroll
            for (int nt = 0; nt < 4; ++nt) o[nt] *= alpha;

            // P^T -> per-wave LDS as Ps[q][kv] (wave-private, no barrier)
#pragma unroll
            for (int nt = 0; nt < 4; ++nt) {
                uint2 pk;
                pk.x = (u32)f2b(v[nt * 4 + 0]) | ((u32)f2b(v[nt * 4 + 1]) << 16);
                pk.y = (u32)f2b(v[nt * 4 + 2]) | ((u32)f2b(v[nt * 4 + 3]) << 16);
                *(uint2*)&Ps[wave][r16][nt * 16 + kq * 4] = pk;
            }

            // O^T += V^T @ P^T : A = Vs rows (d), B = Ps rows (q)
#pragma unroll
            for (int ks = 0; ks < 2; ++ks) {
                const bf16x8 pf = *(const bf16x8*)&Ps[wave][r16][ks * 32 + kq * 8];
#pragma unroll
                for (int nt = 0; nt < 4; ++nt) {
                    const bf16x8 vf = *(const bf16x8*)&Vs[nt * 16 + r16][ks * 32 + kq * 8];
                    o[nt] = MFMA16(vf, pf, o[nt], 0, 0, 0);
                }
            }
        }

        // store: lane owns col q = r16, rows d = nt*16 + kq*4 + j
        const float inv = 1.0f / lrun;
        const size_t row = q0 + wave * 16 + r16;
#pragma unroll
        for (int nt = 0; nt < 4; ++nt) {
            uint2 pk;
            pk.x = (u32)f2b(o[nt][0] * inv) | ((u32)f2b(o[nt][1] * inv) << 16);
            pk.y = (u32)f2b(o[nt][2] * inv) | ((u32)f2b(o[nt][3] * inv) << 16);
            *(uint2*)&ctx[row * D_MODEL + h * DK + nt * 16 + kq * 4] = pk;
        }
    }
}

// ---------------------------------------------------------------------------
extern "C" void kernel_launch(void* const* d_in, const int* in_sizes, int n_in,
                              void* d_out, int out_size, void* d_ws, size_t ws_size,
                              hipStream_t stream) {
    const float* x    = (const float*)d_in[0];
    const float* fcos = (const float*)d_in[1];
    const float* fsin = (const float*)d_in[2];
    const float* Wq = (const float*)d_in[4];
    const float* Wk = (const float*)d_in[5];
    const float* Wv = (const float*)d_in[6];
    const float* Wo = (const float*)d_in[7];
    const float* ln1 = (const float*)d_in[8];
    const float* ln2 = (const float*)d_in[9];
    const float* w1 = (const float*)d_in[10];
    const float* w2 = (const float*)d_in[11];
    const float* w3 = (const float*)d_in[12];
    float* out = (float*)d_out;

    char* ws = (char*)d_ws;
    size_t off = 0;
    auto alloc = [&](size_t bytes) -> char* {
        char* p = ws + off;
        off += (bytes + 255) & ~(size_t)255;
        return p;
    };
    u16* hb    = (u16*)alloc((size_t)S_LEN * D_MODEL * 2);
    u16* wqkvt = (u16*)alloc((size_t)QKV_LD * D_MODEL * 2);  // [3072][1024]
    u16* wot   = (u16*)alloc((size_t)D_MODEL * D_MODEL * 2);
    u16* qkvb  = (u16*)alloc((size_t)S_LEN * QKV_LD * 2);    // [4096][3072]
    u16* vt    = (u16*)alloc((size_t)S_LEN * D_MODEL * 2);   // [H][DK][S]
    u16* kpack = (u16*)alloc((size_t)S_LEN * D_MODEL * 2);   // [H][S][DK]
    u16* ctxb  = (u16*)alloc((size_t)S_LEN * D_MODEL * 2);
    float* x2  = (float*)alloc((size_t)S_LEN * D_MODEL * 4);
    u16* h2b   = (u16*)alloc((size_t)S_LEN * D_MODEL * 2);
    u16* w1t   = (u16*)alloc((size_t)HIDP * D_MODEL * 2);    // [2816][1024]
    u16* w3t   = (u16*)alloc((size_t)HIDP * D_MODEL * 2);
    u16* w2t   = (u16*)alloc((size_t)D_MODEL * HIDP * 2);    // [1024][2816]
    u16* ffb   = (u16*)alloc((size_t)S_LEN * HIDP * 2);      // [4096][2816]

    const dim3 tb32(32, 8);

    // weight transposes (fp32 -> bf16, N x K layout); QKV concatenated
    tcast_k<<<dim3(32, 32), tb32, 0, stream>>>(Wq, D_MODEL, D_MODEL, wqkvt, D_MODEL);
    tcast_k<<<dim3(32, 32), tb32, 0, stream>>>(Wk, D_MODEL, D_MODEL,
                                               wqkvt + (size_t)D_MODEL * D_MODEL, D_MODEL);
    tcast_k<<<dim3(32, 32), tb32, 0, stream>>>(Wv, D_MODEL, D_MODEL,
                                               wqkvt + (size_t)2 * D_MODEL * D_MODEL, D_MODEL);
    tcast_k<<<dim3(32, 32), tb32, 0, stream>>>(Wo, D_MODEL, D_MODEL, wot, D_MODEL);
    tcast_k<<<dim3(32, HIDP / 32), tb32, 0, stream>>>(w1, D_MODEL, HID, w1t, D_MODEL);
    tcast_k<<<dim3(32, HIDP / 32), tb32, 0, stream>>>(w3, D_MODEL, HID, w3t, D_MODEL);
    tcast_k<<<dim3(HIDP / 32, 32), tb32, 0, stream>>>(w2, HID, D_MODEL, w2t, HIDP);

    // h = rmsnorm(x, ln1)
    rmsnorm_k<<<S_LEN, 256, 0, stream>>>(x, ln1, hb);

    // QKV = h @ [Wq|Wk|Wv]   (one 4096x3072x1024 GEMM)
    gemm128<0><<<dim3(QKV_LD / 128, S_LEN / 128), 256, 0, stream>>>(
        hb, D_MODEL, wqkvt, D_MODEL, qkvb, QKV_LD, D_MODEL, nullptr);

    // RoPE on Q,K halves
    rope_k<<<(S_LEN * NHEAD * 32) / 256, 256, 0, stream>>>(qkvb, fcos, fsin);

    // K packed + V transposed per head
    packkv_k<<<dim3(S_LEN / 32, DK / 32, NHEAD), tb32, 0, stream>>>(qkvb, vt, kpack);

    // flash attention (paired q-tiles, XCD-swizzled)
    flash_k<<<dim3(32, NHEAD), 256, 0, stream>>>(qkvb, vt, kpack, ctxb);

    // x2 = x + ctx @ Wo
    gemm128<2><<<dim3(D_MODEL / 128, S_LEN / 128), 256, 0, stream>>>(
        ctxb, D_MODEL, wot, D_MODEL, x2, D_MODEL, D_MODEL, x);

    // h2 = rmsnorm(x2, ln2)
    rmsnorm_k<<<S_LEN, 256, 0, stream>>>(x2, ln2, h2b);

    // ff = silu(h2@w1) * (h2@w3)
    gemm_dual64<<<dim3(HIDP / 64, S_LEN / 128), 256, 0, stream>>>(
        h2b, D_MODEL, w1t, w3t, D_MODEL, ffb, HIDP, D_MODEL);

    // out = x2 + ff @ w2
    gemm128<2><<<dim3(D_MODEL / 128, S_LEN / 128), 256, 0, stream>>>(
        ffb, HIDP, w2t, HIDP, out, D_MODEL, HIDP, x2);
}

// Round 6
// 558.175 us; speedup vs baseline: 1.0101x; 1.0101x over previous
//
#include <hip/hip_runtime.h>

#define S_LEN 4096
#define D_MODEL 1024
#define NHEAD 16
#define DK 64
#define HID 2730
#define HIDP 2816
#define QKV_LD 3072

typedef unsigned short u16;
typedef unsigned int u32;
typedef __bf16 bf16x8 __attribute__((ext_vector_type(8)));
typedef float f32x4 __attribute__((ext_vector_type(4)));

#define MFMA16 __builtin_amdgcn_mfma_f32_16x16x32_bf16

__device__ __forceinline__ float b2f(u16 u) {
    return __builtin_bit_cast(float, (u32)u << 16);
}
__device__ __forceinline__ u16 f2b(float f) {
    u32 u = __builtin_bit_cast(u32, f);
    u += 0x7FFF + ((u >> 16) & 1);
    return (u16)(u >> 16);
}
// async global->LDS, 16B per lane; dest = lds base (wave-uniform) + lane*16
__device__ __forceinline__ void gll16(const u16* g, u16* l) {
    __builtin_amdgcn_global_load_lds(
        (__attribute__((address_space(1))) void*)(g),
        (__attribute__((address_space(3))) void*)(l),
        16, 0, 0);
}

// ---------------------------------------------------------------------------
// RMSNorm: one block per row (D=1024), fp32 in -> bf16 out
// ---------------------------------------------------------------------------
__global__ __launch_bounds__(256)
void rmsnorm_k(const float* __restrict__ x, const float* __restrict__ w,
               u16* __restrict__ out) {
    const int row = blockIdx.x;
    const int tid = threadIdx.x;
    const float4 v = ((const float4*)(x + (size_t)row * D_MODEL))[tid];
    float ss = v.x * v.x + v.y * v.y + v.z * v.z + v.w * v.w;
    for (int o = 32; o; o >>= 1) ss += __shfl_down(ss, o);
    __shared__ float red[4];
    if ((tid & 63) == 0) red[tid >> 6] = ss;
    __syncthreads();
    const float tot = red[0] + red[1] + red[2] + red[3];
    const float rs = rsqrtf(tot * (1.0f / D_MODEL) + 1e-6f);
    const float4 wv = ((const float4*)w)[tid];
    u16* op = out + (size_t)row * D_MODEL + tid * 4;
    u32 p0 = (u32)f2b(v.x * rs * wv.x) | ((u32)f2b(v.y * rs * wv.y) << 16);
    u32 p1 = (u32)f2b(v.z * rs * wv.z) | ((u32)f2b(v.w * rs * wv.w) << 16);
    uint2 pk; pk.x = p0; pk.y = p1;
    *(uint2*)op = pk;
}

// ---------------------------------------------------------------------------
// Tiled transpose + cast fp32 -> bf16.  out[r][c] = in[c][r], zero-padded.
// ---------------------------------------------------------------------------
__global__ __launch_bounds__(256)
void tcast_k(const float* __restrict__ in, int R, int C,
             u16* __restrict__ out, int outC) {
    __shared__ float t[32][33];
    const int r0 = blockIdx.y * 32;
    const int c0 = blockIdx.x * 32;
    const int tx = threadIdx.x, ty = threadIdx.y;
#pragma unroll
    for (int j = 0; j < 4; ++j) {
        int ir = c0 + ty + j * 8;
        int ic = r0 + tx;
        t[ty + j * 8][tx] = (ir < R && ic < C) ? in[(size_t)ir * C + ic] : 0.0f;
    }
    __syncthreads();
#pragma unroll
    for (int j = 0; j < 4; ++j)
        out[(size_t)(r0 + ty + j * 8) * outC + c0 + tx] = f2b(t[tx][ty + j * 8]);
}

// ---------------------------------------------------------------------------
// Pack K/V per head: kp[h][s][d] = qkv[s][1024 + h*64 + d]   (copy)
//                    vt[h][d][s] = qkv[s][2048 + h*64 + d]   (transpose)
// grid: (S/32, DK/32, H), block (32,8)
// ---------------------------------------------------------------------------
__global__ __launch_bounds__(256)
void packkv_k(const u16* __restrict__ qkv, u16* __restrict__ vt,
              u16* __restrict__ kp) {
    __shared__ u16 t[32][33];
    const int h = blockIdx.z;
    const int t0 = blockIdx.x * 32;
    const int d0 = blockIdx.y * 32;
    const int tx = threadIdx.x, ty = threadIdx.y;
#pragma unroll
    for (int j = 0; j < 4; ++j) {
        const int s = t0 + ty + j * 8;
        t[ty + j * 8][tx] = qkv[(size_t)s * QKV_LD + 2 * D_MODEL + h * DK + d0 + tx];
        kp[((size_t)h * S_LEN + s) * DK + d0 + tx] =
            qkv[(size_t)s * QKV_LD + D_MODEL + h * DK + d0 + tx];
    }
    __syncthreads();
#pragma unroll
    for (int j = 0; j < 4; ++j)
        vt[(size_t)h * DK * S_LEN + (size_t)(d0 + ty + j * 8) * S_LEN + t0 + tx] =
            t[tx][ty + j * 8];
}

// ---------------------------------------------------------------------------
// RoPE in place on Q and K halves of qkv buffer (row stride 3072)
// ---------------------------------------------------------------------------
__global__ __launch_bounds__(256)
void rope_k(u16* __restrict__ qkv, const float* __restrict__ fc,
            const float* __restrict__ fs) {
    const int idx = blockIdx.x * 256 + threadIdx.x;   // S*H*32 total
    const int s = idx >> 9;
    const int rem = idx & 511;
    const int h = rem >> 5;
    const int i = rem & 31;
    const size_t base = (size_t)s * QKV_LD + h * DK + 2 * i;
    const float c = fc[s * 32 + i], sn = fs[s * 32 + i];
    u16* q = qkv + base;
    u16* k = qkv + base + D_MODEL;
    float t0 = b2f(q[0]), t1 = b2f(q[1]);
    q[0] = f2b(t0 * c - t1 * sn);
    q[1] = f2b(t0 * sn + t1 * c);
    t0 = b2f(k[0]); t1 = b2f(k[1]);
    k[0] = f2b(t0 * c - t1 * sn);
    k[1] = f2b(t0 * sn + t1 * c);
}

// ---------------------------------------------------------------------------
// 128x128 GEMM (m97 structure): C = A @ Bt^T, global_load_lds staging.
// ---------------------------------------------------------------------------
template <int EPI>
__global__ __launch_bounds__(256)
void gemm128(const u16* __restrict__ A, int lda, const u16* __restrict__ Bt, int ldb,
             void* __restrict__ C, int ldc, int K, const float* __restrict__ resid) {
    const int m0 = blockIdx.y * 128, n0 = blockIdx.x * 128;
    const int tid = threadIdx.x;
    const int wave = tid >> 6, lane = tid & 63;
    const int wr = wave >> 1, wc = wave & 1;
    const int r16 = lane & 15, kq = lane >> 4;

    __shared__ __align__(16) u16 As[128 * 32];
    __shared__ __align__(16) u16 Bs[128 * 32];

    const int srow = tid >> 2, sk = (tid & 3) * 8;
    const u16* ag0 = A + (size_t)(m0 + srow) * lda + sk;
    const u16* ag1 = A + (size_t)(m0 + 64 + srow) * lda + sk;
    const u16* bg0 = Bt + (size_t)(n0 + srow) * ldb + sk;
    const u16* bg1 = Bt + (size_t)(n0 + 64 + srow) * ldb + sk;
    u16* asw = As + wave * 512;
    u16* bsw = Bs + wave * 512;

    f32x4 acc[16];
#pragma unroll
    for (int i = 0; i < 16; ++i) acc[i] = f32x4{0.f, 0.f, 0.f, 0.f};

    for (int k0 = 0; k0 < K; k0 += 32) {
        __syncthreads();
        gll16(ag0 + k0, asw);
        gll16(ag1 + k0, asw + 2048);
        gll16(bg0 + k0, bsw);
        gll16(bg1 + k0, bsw + 2048);
        __syncthreads();
        bf16x8 af[4], bf[4];
#pragma unroll
        for (int mt = 0; mt < 4; ++mt)
            af[mt] = *(const bf16x8*)&As[(wr * 64 + mt * 16 + r16) * 32 + kq * 8];
#pragma unroll
        for (int nt = 0; nt < 4; ++nt)
            bf[nt] = *(const bf16x8*)&Bs[(wc * 64 + nt * 16 + r16) * 32 + kq * 8];
#pragma unroll
        for (int mt = 0; mt < 4; ++mt)
#pragma unroll
            for (int nt = 0; nt < 4; ++nt)
                acc[mt * 4 + nt] = MFMA16(af[mt], bf[nt], acc[mt * 4 + nt], 0, 0, 0);
    }

#pragma unroll
    for (int mt = 0; mt < 4; ++mt) {
#pragma unroll
        for (int nt = 0; nt < 4; ++nt) {
            const int col = n0 + wc * 64 + nt * 16 + r16;
#pragma unroll
            for (int j = 0; j < 4; ++j) {
                const int row = m0 + wr * 64 + mt * 16 + kq * 4 + j;
                if (EPI == 0) {
                    ((u16*)C)[(size_t)row * ldc + col] = f2b(acc[mt * 4 + nt][j]);
                } else {
                    ((float*)C)[(size_t)row * ldc + col] =
                        resid[(size_t)row * ldc + col] + acc[mt * 4 + nt][j];
                }
            }
        }
    }
}

// ---------------------------------------------------------------------------
// FFN dual GEMM: tile 128(M) x 64(N per matrix); ff = silu(A@B1^T)*(A@B3^T)
// ---------------------------------------------------------------------------
__global__ __launch_bounds__(256)
void gemm_dual64(const u16* __restrict__ A, int lda,
                 const u16* __restrict__ B1, const u16* __restrict__ B3, int ldb,
                 u16* __restrict__ C, int ldc, int K) {
    const int m0 = blockIdx.y * 128, n0 = blockIdx.x * 64;
    const int tid = threadIdx.x;
    const int wave = tid >> 6, lane = tid & 63;
    const int r16 = lane & 15, kq = lane >> 4;

    __shared__ __align__(16) u16 As[128 * 32];
    __shared__ __align__(16) u16 B1s[64 * 32];
    __shared__ __align__(16) u16 B3s[64 * 32];

    const int srow = tid >> 2, sk = (tid & 3) * 8;
    const u16* ag0 = A + (size_t)(m0 + srow) * lda + sk;
    const u16* ag1 = A + (size_t)(m0 + 64 + srow) * lda + sk;
    const u16* b1g = B1 + (size_t)(n0 + srow) * ldb + sk;
    const u16* b3g = B3 + (size_t)(n0 + srow) * ldb + sk;
    u16* asw = As + wave * 512;
    u16* b1w = B1s + wave * 512;
    u16* b3w = B3s + wave * 512;

    f32x4 acc1[8], acc3[8];
#pragma unroll
    for (int i = 0; i < 8; ++i) {
        acc1[i] = f32x4{0.f, 0.f, 0.f, 0.f};
        acc3[i] = f32x4{0.f, 0.f, 0.f, 0.f};
    }

    for (int k0 = 0; k0 < K; k0 += 32) {
        __syncthreads();
        gll16(ag0 + k0, asw);
        gll16(ag1 + k0, asw + 2048);
        gll16(b1g + k0, b1w);
        gll16(b3g + k0, b3w);
        __syncthreads();
        bf16x8 af[2], b1f[4], b3f[4];
#pragma unroll
        for (int mt = 0; mt < 2; ++mt)
            af[mt] = *(const bf16x8*)&As[(wave * 32 + mt * 16 + r16) * 32 + kq * 8];
#pragma unroll
        for (int nt = 0; nt < 4; ++nt) {
            b1f[nt] = *(const bf16x8*)&B1s[(nt * 16 + r16) * 32 + kq * 8];
            b3f[nt] = *(const bf16x8*)&B3s[(nt * 16 + r16) * 32 + kq * 8];
        }
#pragma unroll
        for (int mt = 0; mt < 2; ++mt)
#pragma unroll
            for (int nt = 0; nt < 4; ++nt) {
                acc1[mt * 4 + nt] = MFMA16(af[mt], b1f[nt], acc1[mt * 4 + nt], 0, 0, 0);
                acc3[mt * 4 + nt] = MFMA16(af[mt], b3f[nt], acc3[mt * 4 + nt], 0, 0, 0);
            }
    }

#pragma unroll
    for (int mt = 0; mt < 2; ++mt)
#pragma unroll
        for (int nt = 0; nt < 4; ++nt) {
            const int col = n0 + nt * 16 + r16;
#pragma unroll
            for (int j = 0; j < 4; ++j) {
                const int row = m0 + wave * 32 + mt * 16 + kq * 4 + j;
                const float v1 = acc1[mt * 4 + nt][j];
                const float v3 = acc3[mt * 4 + nt][j];
                const float sig = 1.0f / (1.0f + __expf(-v1));
                C[(size_t)row * ldc + col] = f2b(v1 * sig * v3);
            }
        }
}

// ---------------------------------------------------------------------------
// Flash attention: TWO q-tiles per block processed CONCURRENTLY through one
// kv sweep (K/V staged once, 2x softmax ILP). Natural block order: x = pair
// slot (cost-balanced mapping), y = head -> consecutive blocks share a head
// (L2 locality). S^T formulation: per-lane softmax state, lane-local rescale.
// ---------------------------------------------------------------------------
__global__ __launch_bounds__(256)
void flash_k(const u16* __restrict__ qkv, const u16* __restrict__ vt,
             const u16* __restrict__ kp, u16* __restrict__ ctx) {
    const int h = blockIdx.y;
    const int jx = blockIdx.x;                               // 0..31
    const int pair = (jx & 1) ? (31 - (jx >> 1)) : (jx >> 1); // balance adjacents
    const int qiA = pair, qiB = 63 - pair;                   // qiB > qiA
    const int q0A = qiA * 64, q0B = qiB * 64;
    const int tid = threadIdx.x;
    const int wave = tid >> 6, lane = tid & 63;
    const int r16 = lane & 15, kq = lane >> 4;

    __shared__ __align__(16) u16 Ks[64][72];     // [kv][dk]
    __shared__ __align__(16) u16 Vs[64][72];     // [dk][kv]
    __shared__ __align__(16) u16 PsA[4][16][72]; // per-wave [q][kv]
    __shared__ __align__(16) u16 PsB[4][16][72];

    const u16* kb = kp + (size_t)h * S_LEN * DK;
    const u16* vbase = vt + (size_t)h * DK * S_LEN;
    const int ldr = tid >> 3, ldc_ = (tid & 7) * 8;
    const float SC = 0.125f * 1.44269504f;       // scale * log2(e)
    const int qloc = wave * 16 + r16;

    const u16* qrowA = qkv + (size_t)(q0A + qloc) * QKV_LD + h * DK;
    const bf16x8 qA0 = *(const bf16x8*)(qrowA + kq * 8);
    const bf16x8 qA1 = *(const bf16x8*)(qrowA + 32 + kq * 8);
    const u16* qrowB = qkv + (size_t)(q0B + qloc) * QKV_LD + h * DK;
    const bf16x8 qB0 = *(const bf16x8*)(qrowB + kq * 8);
    const bf16x8 qB1 = *(const bf16x8*)(qrowB + 32 + kq * 8);

    f32x4 oA[4], oB[4];
#pragma unroll
    for (int i = 0; i < 4; ++i) {
        oA[i] = f32x4{0.f, 0.f, 0.f, 0.f};
        oB[i] = f32x4{0.f, 0.f, 0.f, 0.f};
    }
    float mA = -1e30f, lA = 0.f, mB = -1e30f, lB = 0.f;

    // prefetch tile 0
    uint4 kpr[2], vpr[2];
#pragma unroll
    for (int i = 0; i < 2; ++i) {
        const int r = ldr + i * 32;
        kpr[i] = *(const uint4*)(kb + (size_t)r * DK + ldc_);
        vpr[i] = *(const uint4*)(vbase + (size_t)r * S_LEN + ldc_);
    }

    for (int t = 0; t <= qiB; ++t) {
        __syncthreads();
#pragma unroll
        for (int i = 0; i < 2; ++i) {
            const int r = ldr + i * 32;
            *(uint4*)&Ks[r][ldc_] = kpr[i];
            *(uint4*)&Vs[r][ldc_] = vpr[i];
        }
        __syncthreads();
        if (t < qiB) {   // prefetch next tile during compute
            const int t1 = (t + 1) * 64;
#pragma unroll
            for (int i = 0; i < 2; ++i) {
                const int r = ldr + i * 32;
                kpr[i] = *(const uint4*)(kb + (size_t)(t1 + r) * DK + ldc_);
                vpr[i] = *(const uint4*)(vbase + (size_t)r * S_LEN + t1 + ldc_);
            }
        }

        // K fragments (shared by both q-tiles)
        bf16x8 kf0[4], kf1[4];
#pragma unroll
        for (int nt = 0; nt < 4; ++nt) {
            kf0[nt] = *(const bf16x8*)&Ks[nt * 16 + r16][kq * 8];
            kf1[nt] = *(const bf16x8*)&Ks[nt * 16 + r16][32 + kq * 8];
        }

        // QK^T + online softmax for one q-tile (S^T: col=q=r16 per lane)
        auto qk_soft = [&](const bf16x8& q0f, const bf16x8& q1f, float& mrun,
                           float& lrun, f32x4* o, u16* PsW, bool diag) {
            f32x4 s[4];
#pragma unroll
            for (int nt = 0; nt < 4; ++nt) {
                s[nt] = f32x4{0.f, 0.f, 0.f, 0.f};
                s[nt] = MFMA16(kf0[nt], q0f, s[nt], 0, 0, 0);
                s[nt] = MFMA16(kf1[nt], q1f, s[nt], 0, 0, 0);
            }
            float v[16];
#pragma unroll
            for (int nt = 0; nt < 4; ++nt)
#pragma unroll
                for (int j = 0; j < 4; ++j) v[nt * 4 + j] = s[nt][j] * SC;
            if (diag) {
#pragma unroll
                for (int nt = 0; nt < 4; ++nt)
#pragma unroll
                    for (int j = 0; j < 4; ++j)
                        if ((nt * 16 + kq * 4 + j) > qloc) v[nt * 4 + j] = -1e9f;
            }
            float red[8];
#pragma unroll
            for (int i = 0; i < 8; ++i) red[i] = fmaxf(v[2 * i], v[2 * i + 1]);
#pragma unroll
            for (int w2 = 4; w2; w2 >>= 1)
#pragma unroll
                for (int i = 0; i < 8; ++i)
                    if (i < w2) red[i] = fmaxf(red[2 * i], red[2 * i + 1]);
            float lm = red[0];
            lm = fmaxf(lm, __shfl_xor(lm, 16));
            lm = fmaxf(lm, __shfl_xor(lm, 32));
            const float mnew = fmaxf(mrun, lm);
            const float alpha = exp2f(mrun - mnew);
            mrun = mnew;
#pragma unroll
            for (int i = 0; i < 16; ++i) v[i] = exp2f(v[i] - mnew);
#pragma unroll
            for (int i = 0; i < 8; ++i) red[i] = v[2 * i] + v[2 * i + 1];
#pragma unroll
            for (int w2 = 4; w2; w2 >>= 1)
#pragma unroll
                for (int i = 0; i < 8; ++i)
                    if (i < w2) red[i] = red[2 * i] + red[2 * i + 1];
            float rs = red[0];
            rs += __shfl_xor(rs, 16);
            rs += __shfl_xor(rs, 32);
            lrun = lrun * alpha + rs;
#pragma unroll
            for (int nt = 0; nt < 4; ++nt) o[nt] *= alpha;
            // P^T -> wave-private LDS [q=r16][kv]
#pragma unroll
            for (int nt = 0; nt < 4; ++nt) {
                uint2 pk;
                pk.x = (u32)f2b(v[nt * 4 + 0]) | ((u32)f2b(v[nt * 4 + 1]) << 16);
                pk.y = (u32)f2b(v[nt * 4 + 2]) | ((u32)f2b(v[nt * 4 + 3]) << 16);
                *(uint2*)&PsW[r16 * 72 + nt * 16 + kq * 4] = pk;
            }
        };

        const bool actA = (t <= qiA);
        qk_soft(qB0, qB1, mB, lB, oB, &PsB[wave][0][0], t == qiB);
        if (actA) qk_soft(qA0, qA1, mA, lA, oA, &PsA[wave][0][0], t == qiA);

        // PV: O^T += V^T @ P^T (V frags shared)
        if (actA) {
#pragma unroll
            for (int ks = 0; ks < 2; ++ks) {
                const bf16x8 pfB = *(const bf16x8*)&PsB[wave][r16][ks * 32 + kq * 8];
                const bf16x8 pfA = *(const bf16x8*)&PsA[wave][r16][ks * 32 + kq * 8];
#pragma unroll
                for (int nt = 0; nt < 4; ++nt) {
                    const bf16x8 vf = *(const bf16x8*)&Vs[nt * 16 + r16][ks * 32 + kq * 8];
                    oB[nt] = MFMA16(vf, pfB, oB[nt], 0, 0, 0);
                    oA[nt] = MFMA16(vf, pfA, oA[nt], 0, 0, 0);
                }
            }
        } else {
#pragma unroll
            for (int ks = 0; ks < 2; ++ks) {
                const bf16x8 pfB = *(const bf16x8*)&PsB[wave][r16][ks * 32 + kq * 8];
#pragma unroll
                for (int nt = 0; nt < 4; ++nt) {
                    const bf16x8 vf = *(const bf16x8*)&Vs[nt * 16 + r16][ks * 32 + kq * 8];
                    oB[nt] = MFMA16(vf, pfB, oB[nt], 0, 0, 0);
                }
            }
        }
    }

    // store both tiles: lane owns col q=r16, rows d = nt*16 + kq*4 + j
    const float invA = 1.0f / lA, invB = 1.0f / lB;
    const size_t rowA = q0A + qloc, rowB = q0B + qloc;
#pragma unroll
    for (int nt = 0; nt < 4; ++nt) {
        uint2 pa, pb;
        pa.x = (u32)f2b(oA[nt][0] * invA) | ((u32)f2b(oA[nt][1] * invA) << 16);
        pa.y = (u32)f2b(oA[nt][2] * invA) | ((u32)f2b(oA[nt][3] * invA) << 16);
        pb.x = (u32)f2b(oB[nt][0] * invB) | ((u32)f2b(oB[nt][1] * invB) << 16);
        pb.y = (u32)f2b(oB[nt][2] * invB) | ((u32)f2b(oB[nt][3] * invB) << 16);
        *(uint2*)&ctx[rowA * D_MODEL + h * DK + nt * 16 + kq * 4] = pa;
        *(uint2*)&ctx[rowB * D_MODEL + h * DK + nt * 16 + kq * 4] = pb;
    }
}

// ---------------------------------------------------------------------------
extern "C" void kernel_launch(void* const* d_in, const int* in_sizes, int n_in,
                              void* d_out, int out_size, void* d_ws, size_t ws_size,
                              hipStream_t stream) {
    const float* x    = (const float*)d_in[0];
    const float* fcos = (const float*)d_in[1];
    const float* fsin = (const float*)d_in[2];
    const float* Wq = (const float*)d_in[4];
    const float* Wk = (const float*)d_in[5];
    const float* Wv = (const float*)d_in[6];
    const float* Wo = (const float*)d_in[7];
    const float* ln1 = (const float*)d_in[8];
    const float* ln2 = (const float*)d_in[9];
    const float* w1 = (const float*)d_in[10];
    const float* w2 = (const float*)d_in[11];
    const float* w3 = (const float*)d_in[12];
    float* out = (float*)d_out;

    char* ws = (char*)d_ws;
    size_t off = 0;
    auto alloc = [&](size_t bytes) -> char* {
        char* p = ws + off;
        off += (bytes + 255) & ~(size_t)255;
        return p;
    };
    u16* hb    = (u16*)alloc((size_t)S_LEN * D_MODEL * 2);
    u16* wqkvt = (u16*)alloc((size_t)QKV_LD * D_MODEL * 2);  // [3072][1024]
    u16* wot   = (u16*)alloc((size_t)D_MODEL * D_MODEL * 2);
    u16* qkvb  = (u16*)alloc((size_t)S_LEN * QKV_LD * 2);    // [4096][3072]
    u16* vt    = (u16*)alloc((size_t)S_LEN * D_MODEL * 2);   // [H][DK][S]
    u16* kpack = (u16*)alloc((size_t)S_LEN * D_MODEL * 2);   // [H][S][DK]
    u16* ctxb  = (u16*)alloc((size_t)S_LEN * D_MODEL * 2);
    float* x2  = (float*)alloc((size_t)S_LEN * D_MODEL * 4);
    u16* h2b   = (u16*)alloc((size_t)S_LEN * D_MODEL * 2);
    u16* w1t   = (u16*)alloc((size_t)HIDP * D_MODEL * 2);    // [2816][1024]
    u16* w3t   = (u16*)alloc((size_t)HIDP * D_MODEL * 2);
    u16* w2t   = (u16*)alloc((size_t)D_MODEL * HIDP * 2);    // [1024][2816]
    u16* ffb   = (u16*)alloc((size_t)S_LEN * HIDP * 2);      // [4096][2816]

    const dim3 tb32(32, 8);

    // weight transposes (fp32 -> bf16, N x K layout); QKV concatenated
    tcast_k<<<dim3(32, 32), tb32, 0, stream>>>(Wq, D_MODEL, D_MODEL, wqkvt, D_MODEL);
    tcast_k<<<dim3(32, 32), tb32, 0, stream>>>(Wk, D_MODEL, D_MODEL,
                                               wqkvt + (size_t)D_MODEL * D_MODEL, D_MODEL);
    tcast_k<<<dim3(32, 32), tb32, 0, stream>>>(Wv, D_MODEL, D_MODEL,
                                               wqkvt + (size_t)2 * D_MODEL * D_MODEL, D_MODEL);
    tcast_k<<<dim3(32, 32), tb32, 0, stream>>>(Wo, D_MODEL, D_MODEL, wot, D_MODEL);
    tcast_k<<<dim3(32, HIDP / 32), tb32, 0, stream>>>(w1, D_MODEL, HID, w1t, D_MODEL);
    tcast_k<<<dim3(32, HIDP / 32), tb32, 0, stream>>>(w3, D_MODEL, HID, w3t, D_MODEL);
    tcast_k<<<dim3(HIDP / 32, 32), tb32, 0, stream>>>(w2, HID, D_MODEL, w2t, HIDP);

    // h = rmsnorm(x, ln1)
    rmsnorm_k<<<S_LEN, 256, 0, stream>>>(x, ln1, hb);

    // QKV = h @ [Wq|Wk|Wv]   (one 4096x3072x1024 GEMM)
    gemm128<0><<<dim3(QKV_LD / 128, S_LEN / 128), 256, 0, stream>>>(
        hb, D_MODEL, wqkvt, D_MODEL, qkvb, QKV_LD, D_MODEL, nullptr);

    // RoPE on Q,K halves
    rope_k<<<(S_LEN * NHEAD * 32) / 256, 256, 0, stream>>>(qkvb, fcos, fsin);

    // K packed + V transposed per head
    packkv_k<<<dim3(S_LEN / 32, DK / 32, NHEAD), tb32, 0, stream>>>(qkvb, vt, kpack);

    // flash attention (two concurrent q-tiles per block, natural head order)
    flash_k<<<dim3(32, NHEAD), 256, 0, stream>>>(qkvb, vt, kpack, ctxb);

    // x2 = x + ctx @ Wo
    gemm128<2><<<dim3(D_MODEL / 128, S_LEN / 128), 256, 0, stream>>>(
        ctxb, D_MODEL, wot, D_MODEL, x2, D_MODEL, D_MODEL, x);

    // h2 = rmsnorm(x2, ln2)
    rmsnorm_k<<<S_LEN, 256, 0, stream>>>(x2, ln2, h2b);

    // ff = silu(h2@w1) * (h2@w3)
    gemm_dual64<<<dim3(HIDP / 64, S_LEN / 128), 256, 0, stream>>>(
        h2b, D_MODEL, w1t, w3t, D_MODEL, ffb, HIDP, D_MODEL);

    // out = x2 + ff @ w2
    gemm128<2><<<dim3(D_MODEL / 128, S_LEN / 128), 256, 0, stream>>>(
        ffb, HIDP, w2t, HIDP, out, D_MODEL, HIDP, x2);
}

// Round 7
// 505.849 us; speedup vs baseline: 1.1146x; 1.1034x over previous
//
#include <hip/hip_runtime.h>

#define S_LEN 4096
#define D_MODEL 1024
#define NHEAD 16
#define DK 64
#define HID 2730
#define HIDP 2816
#define QKV_LD 3072

typedef unsigned short u16;
typedef unsigned int u32;
typedef __bf16 bf16x8 __attribute__((ext_vector_type(8)));
typedef float f32x4 __attribute__((ext_vector_type(4)));

#define MFMA16 __builtin_amdgcn_mfma_f32_16x16x32_bf16

__device__ __forceinline__ float b2f(u16 u) {
    return __builtin_bit_cast(float, (u32)u << 16);
}
__device__ __forceinline__ u16 f2b(float f) {
    u32 u = __builtin_bit_cast(u32, f);
    u += 0x7FFF + ((u >> 16) & 1);
    return (u16)(u >> 16);
}
// pack two f32 -> two bf16 (truncate) in one v_perm_b32
__device__ __forceinline__ u32 pk_trunc(float lo, float hi) {
    return __builtin_amdgcn_perm(__builtin_bit_cast(u32, hi),
                                 __builtin_bit_cast(u32, lo), 0x07060302u);
}
// async global->LDS, 16B per lane
__device__ __forceinline__ void gll16(const u16* g, u16* l) {
    __builtin_amdgcn_global_load_lds(
        (__attribute__((address_space(1))) void*)(g),
        (__attribute__((address_space(3))) void*)(l),
        16, 0, 0);
}

// ---------------------------------------------------------------------------
// RMSNorm: one block per row (D=1024), fp32 in -> bf16 out
// ---------------------------------------------------------------------------
__global__ __launch_bounds__(256)
void rmsnorm_k(const float* __restrict__ x, const float* __restrict__ w,
               u16* __restrict__ out) {
    const int row = blockIdx.x;
    const int tid = threadIdx.x;
    const float4 v = ((const float4*)(x + (size_t)row * D_MODEL))[tid];
    float ss = v.x * v.x + v.y * v.y + v.z * v.z + v.w * v.w;
    for (int o = 32; o; o >>= 1) ss += __shfl_down(ss, o);
    __shared__ float red[4];
    if ((tid & 63) == 0) red[tid >> 6] = ss;
    __syncthreads();
    const float tot = red[0] + red[1] + red[2] + red[3];
    const float rs = rsqrtf(tot * (1.0f / D_MODEL) + 1e-6f);
    const float4 wv = ((const float4*)w)[tid];
    u16* op = out + (size_t)row * D_MODEL + tid * 4;
    u32 p0 = (u32)f2b(v.x * rs * wv.x) | ((u32)f2b(v.y * rs * wv.y) << 16);
    u32 p1 = (u32)f2b(v.z * rs * wv.z) | ((u32)f2b(v.w * rs * wv.w) << 16);
    uint2 pk; pk.x = p0; pk.y = p1;
    *(uint2*)op = pk;
}

// ---------------------------------------------------------------------------
// Tiled transpose + cast fp32 -> bf16.  out[r][c] = in[c][r], zero-padded.
// ---------------------------------------------------------------------------
__global__ __launch_bounds__(256)
void tcast_k(const float* __restrict__ in, int R, int C,
             u16* __restrict__ out, int outC) {
    __shared__ float t[32][33];
    const int r0 = blockIdx.y * 32;
    const int c0 = blockIdx.x * 32;
    const int tx = threadIdx.x, ty = threadIdx.y;
#pragma unroll
    for (int j = 0; j < 4; ++j) {
        int ir = c0 + ty + j * 8;
        int ic = r0 + tx;
        t[ty + j * 8][tx] = (ir < R && ic < C) ? in[(size_t)ir * C + ic] : 0.0f;
    }
    __syncthreads();
#pragma unroll
    for (int j = 0; j < 4; ++j)
        out[(size_t)(r0 + ty + j * 8) * outC + c0 + tx] = f2b(t[tx][ty + j * 8]);
}

// ---------------------------------------------------------------------------
// Pack K/V per head: kp[h][s][d] = qkv[s][1024 + h*64 + d]   (copy)
//                    vt[h][d][s] = qkv[s][2048 + h*64 + d]   (transpose)
// ---------------------------------------------------------------------------
__global__ __launch_bounds__(256)
void packkv_k(const u16* __restrict__ qkv, u16* __restrict__ vt,
              u16* __restrict__ kp) {
    __shared__ u16 t[32][33];
    const int h = blockIdx.z;
    const int t0 = blockIdx.x * 32;
    const int d0 = blockIdx.y * 32;
    const int tx = threadIdx.x, ty = threadIdx.y;
#pragma unroll
    for (int j = 0; j < 4; ++j) {
        const int s = t0 + ty + j * 8;
        t[ty + j * 8][tx] = qkv[(size_t)s * QKV_LD + 2 * D_MODEL + h * DK + d0 + tx];
        kp[((size_t)h * S_LEN + s) * DK + d0 + tx] =
            qkv[(size_t)s * QKV_LD + D_MODEL + h * DK + d0 + tx];
    }
    __syncthreads();
#pragma unroll
    for (int j = 0; j < 4; ++j)
        vt[(size_t)h * DK * S_LEN + (size_t)(d0 + ty + j * 8) * S_LEN + t0 + tx] =
            t[tx][ty + j * 8];
}

// ---------------------------------------------------------------------------
// RoPE in place; Q additionally scaled by 0.125*log2(e) (Q only feeds QK^T,
// letting flash_k skip the per-score scale mul and run exp2-space softmax).
// ---------------------------------------------------------------------------
__global__ __launch_bounds__(256)
void rope_k(u16* __restrict__ qkv, const float* __restrict__ fc,
            const float* __restrict__ fs) {
    const int idx = blockIdx.x * 256 + threadIdx.x;   // S*H*32 total
    const int s = idx >> 9;
    const int rem = idx & 511;
    const int h = rem >> 5;
    const int i = rem & 31;
    const size_t base = (size_t)s * QKV_LD + h * DK + 2 * i;
    const float c = fc[s * 32 + i], sn = fs[s * 32 + i];
    const float SC = 0.125f * 1.44269504f;
    u16* q = qkv + base;
    u16* k = qkv + base + D_MODEL;
    float t0 = b2f(q[0]), t1 = b2f(q[1]);
    q[0] = f2b((t0 * c - t1 * sn) * SC);
    q[1] = f2b((t0 * sn + t1 * c) * SC);
    t0 = b2f(k[0]); t1 = b2f(k[1]);
    k[0] = f2b(t0 * c - t1 * sn);
    k[1] = f2b(t0 * sn + t1 * c);
}

// ---------------------------------------------------------------------------
// 128x128 GEMM (m97 structure): C = A @ Bt^T, global_load_lds staging.
// ---------------------------------------------------------------------------
template <int EPI>
__global__ __launch_bounds__(256)
void gemm128(const u16* __restrict__ A, int lda, const u16* __restrict__ Bt, int ldb,
             void* __restrict__ C, int ldc, int K, const float* __restrict__ resid) {
    const int m0 = blockIdx.y * 128, n0 = blockIdx.x * 128;
    const int tid = threadIdx.x;
    const int wave = tid >> 6, lane = tid & 63;
    const int wr = wave >> 1, wc = wave & 1;
    const int r16 = lane & 15, kq = lane >> 4;

    __shared__ __align__(16) u16 As[128 * 32];
    __shared__ __align__(16) u16 Bs[128 * 32];

    const int srow = tid >> 2, sk = (tid & 3) * 8;
    const u16* ag0 = A + (size_t)(m0 + srow) * lda + sk;
    const u16* ag1 = A + (size_t)(m0 + 64 + srow) * lda + sk;
    const u16* bg0 = Bt + (size_t)(n0 + srow) * ldb + sk;
    const u16* bg1 = Bt + (size_t)(n0 + 64 + srow) * ldb + sk;
    u16* asw = As + wave * 512;
    u16* bsw = Bs + wave * 512;

    f32x4 acc[16];
#pragma unroll
    for (int i = 0; i < 16; ++i) acc[i] = f32x4{0.f, 0.f, 0.f, 0.f};

    for (int k0 = 0; k0 < K; k0 += 32) {
        __syncthreads();
        gll16(ag0 + k0, asw);
        gll16(ag1 + k0, asw + 2048);
        gll16(bg0 + k0, bsw);
        gll16(bg1 + k0, bsw + 2048);
        __syncthreads();
        bf16x8 af[4], bf[4];
#pragma unroll
        for (int mt = 0; mt < 4; ++mt)
            af[mt] = *(const bf16x8*)&As[(wr * 64 + mt * 16 + r16) * 32 + kq * 8];
#pragma unroll
        for (int nt = 0; nt < 4; ++nt)
            bf[nt] = *(const bf16x8*)&Bs[(wc * 64 + nt * 16 + r16) * 32 + kq * 8];
#pragma unroll
        for (int mt = 0; mt < 4; ++mt)
#pragma unroll
            for (int nt = 0; nt < 4; ++nt)
                acc[mt * 4 + nt] = MFMA16(af[mt], bf[nt], acc[mt * 4 + nt], 0, 0, 0);
    }

#pragma unroll
    for (int mt = 0; mt < 4; ++mt) {
#pragma unroll
        for (int nt = 0; nt < 4; ++nt) {
            const int col = n0 + wc * 64 + nt * 16 + r16;
#pragma unroll
            for (int j = 0; j < 4; ++j) {
                const int row = m0 + wr * 64 + mt * 16 + kq * 4 + j;
                if (EPI == 0) {
                    ((u16*)C)[(size_t)row * ldc + col] = f2b(acc[mt * 4 + nt][j]);
                } else {
                    ((float*)C)[(size_t)row * ldc + col] =
                        resid[(size_t)row * ldc + col] + acc[mt * 4 + nt][j];
                }
            }
        }
    }
}

// ---------------------------------------------------------------------------
// FFN dual GEMM: tile 128(M) x 64(N per matrix); ff = silu(A@B1^T)*(A@B3^T)
// ---------------------------------------------------------------------------
__global__ __launch_bounds__(256)
void gemm_dual64(const u16* __restrict__ A, int lda,
                 const u16* __restrict__ B1, const u16* __restrict__ B3, int ldb,
                 u16* __restrict__ C, int ldc, int K) {
    const int m0 = blockIdx.y * 128, n0 = blockIdx.x * 64;
    const int tid = threadIdx.x;
    const int wave = tid >> 6, lane = tid & 63;
    const int r16 = lane & 15, kq = lane >> 4;

    __shared__ __align__(16) u16 As[128 * 32];
    __shared__ __align__(16) u16 B1s[64 * 32];
    __shared__ __align__(16) u16 B3s[64 * 32];

    const int srow = tid >> 2, sk = (tid & 3) * 8;
    const u16* ag0 = A + (size_t)(m0 + srow) * lda + sk;
    const u16* ag1 = A + (size_t)(m0 + 64 + srow) * lda + sk;
    const u16* b1g = B1 + (size_t)(n0 + srow) * ldb + sk;
    const u16* b3g = B3 + (size_t)(n0 + srow) * ldb + sk;
    u16* asw = As + wave * 512;
    u16* b1w = B1s + wave * 512;
    u16* b3w = B3s + wave * 512;

    f32x4 acc1[8], acc3[8];
#pragma unroll
    for (int i = 0; i < 8; ++i) {
        acc1[i] = f32x4{0.f, 0.f, 0.f, 0.f};
        acc3[i] = f32x4{0.f, 0.f, 0.f, 0.f};
    }

    for (int k0 = 0; k0 < K; k0 += 32) {
        __syncthreads();
        gll16(ag0 + k0, asw);
        gll16(ag1 + k0, asw + 2048);
        gll16(b1g + k0, b1w);
        gll16(b3g + k0, b3w);
        __syncthreads();
        bf16x8 af[2], b1f[4], b3f[4];
#pragma unroll
        for (int mt = 0; mt < 2; ++mt)
            af[mt] = *(const bf16x8*)&As[(wave * 32 + mt * 16 + r16) * 32 + kq * 8];
#pragma unroll
        for (int nt = 0; nt < 4; ++nt) {
            b1f[nt] = *(const bf16x8*)&B1s[(nt * 16 + r16) * 32 + kq * 8];
            b3f[nt] = *(const bf16x8*)&B3s[(nt * 16 + r16) * 32 + kq * 8];
        }
#pragma unroll
        for (int mt = 0; mt < 2; ++mt)
#pragma unroll
            for (int nt = 0; nt < 4; ++nt) {
                acc1[mt * 4 + nt] = MFMA16(af[mt], b1f[nt], acc1[mt * 4 + nt], 0, 0, 0);
                acc3[mt * 4 + nt] = MFMA16(af[mt], b3f[nt], acc3[mt * 4 + nt], 0, 0, 0);
            }
    }

#pragma unroll
    for (int mt = 0; mt < 2; ++mt)
#pragma unroll
        for (int nt = 0; nt < 4; ++nt) {
            const int col = n0 + nt * 16 + r16;
#pragma unroll
            for (int j = 0; j < 4; ++j) {
                const int row = m0 + wave * 32 + mt * 16 + kq * 4 + j;
                const float v1 = acc1[mt * 4 + nt][j];
                const float v3 = acc3[mt * 4 + nt][j];
                const float sig = 1.0f / (1.0f + __expf(-v1));
                C[(size_t)row * ldc + col] = f2b(v1 * sig * v3);
            }
        }
}

// ---------------------------------------------------------------------------
// Flash attention v3: S^T form, NO online max (scores bounded: |s*scale*lg2e|
// <~5, exp2 safe in fp32 by >30 orders), l = per-lane partial sum reduced
// cross-quad ONCE at the end. Zero per-iter cross-lane ops. P packed via
// v_perm (truncating bf16). Q pre-scaled in rope_k.
// Grid (head=bx, 64=by); by->qi mapping gives complementary qi per CU under
// round-robin dispatch (c, c+256, ...: same head, qi={b,63-b,b+16,47-b}).
// ---------------------------------------------------------------------------
__global__ __launch_bounds__(256)
void flash_k(const u16* __restrict__ qkv, const u16* __restrict__ vt,
             const u16* __restrict__ kp, u16* __restrict__ ctx) {
    const int h = blockIdx.x;
    const int by = blockIdx.y;
    const int hi = by >> 4, lo = by & 15;
    const int base = lo + ((hi >> 1) << 4);
    const int qi = (hi & 1) ? (63 - base) : base;
    const int q0 = qi * 64;
    const int tid = threadIdx.x;
    const int wave = tid >> 6, lane = tid & 63;
    const int r16 = lane & 15, kq = lane >> 4;

    __shared__ __align__(16) u16 Ks[64][72];    // [kv][dk]
    __shared__ __align__(16) u16 Vs[64][72];    // [dk][kv]
    __shared__ __align__(16) u16 Ps[4][16][72]; // per-wave [q][kv]

    const u16* kb = kp + (size_t)h * S_LEN * DK;
    const u16* vbase = vt + (size_t)h * DK * S_LEN;
    const int ldr = tid >> 3, ldc_ = (tid & 7) * 8;
    const int qloc = wave * 16 + r16;

    const u16* qrow = qkv + (size_t)(q0 + qloc) * QKV_LD + h * DK;
    const bf16x8 qf0 = *(const bf16x8*)(qrow + kq * 8);
    const bf16x8 qf1 = *(const bf16x8*)(qrow + 32 + kq * 8);

    f32x4 o[4];
#pragma unroll
    for (int i = 0; i < 4; ++i) o[i] = f32x4{0.f, 0.f, 0.f, 0.f};
    float lpart = 0.f;

    for (int t = 0; t <= qi; ++t) {
        const int t0 = t * 64;
        __syncthreads();
#pragma unroll
        for (int i = 0; i < 2; ++i) {
            const int r = ldr + i * 32;
            *(uint4*)&Ks[r][ldc_] = *(const uint4*)(kb + (size_t)(t0 + r) * DK + ldc_);
            *(uint4*)&Vs[r][ldc_] = *(const uint4*)(vbase + (size_t)r * S_LEN + t0 + ldc_);
        }
        __syncthreads();

        // S^T[kv][q] = K·Q^T (Q pre-scaled): col=q=r16 per lane
        f32x4 s[4];
#pragma unroll
        for (int nt = 0; nt < 4; ++nt) {
            s[nt] = f32x4{0.f, 0.f, 0.f, 0.f};
            const bf16x8 k0 = *(const bf16x8*)&Ks[nt * 16 + r16][kq * 8];
            s[nt] = MFMA16(k0, qf0, s[nt], 0, 0, 0);
            const bf16x8 k1 = *(const bf16x8*)&Ks[nt * 16 + r16][32 + kq * 8];
            s[nt] = MFMA16(k1, qf1, s[nt], 0, 0, 0);
        }

        // p = 2^s, diag-masked to 0; accumulate per-lane l partial
        float p[16];
#pragma unroll
        for (int nt = 0; nt < 4; ++nt)
#pragma unroll
            for (int j = 0; j < 4; ++j) p[nt * 4 + j] = exp2f(s[nt][j]);
        if (t == qi) {
#pragma unroll
            for (int nt = 0; nt < 4; ++nt)
#pragma unroll
                for (int j = 0; j < 4; ++j)
                    if ((nt * 16 + kq * 4 + j) > qloc) p[nt * 4 + j] = 0.f;
        }
#pragma unroll
        for (int i = 0; i < 16; ++i) lpart += p[i];

        // P^T -> wave-private LDS [q][kv], truncating bf16 pack (v_perm)
#pragma unroll
        for (int nt = 0; nt < 4; ++nt) {
            uint2 pk;
            pk.x = pk_trunc(p[nt * 4 + 0], p[nt * 4 + 1]);
            pk.y = pk_trunc(p[nt * 4 + 2], p[nt * 4 + 3]);
            *(uint2*)&Ps[wave][r16][nt * 16 + kq * 4] = pk;
        }

        // O^T += V^T @ P^T
#pragma unroll
        for (int ks = 0; ks < 2; ++ks) {
            const bf16x8 pf = *(const bf16x8*)&Ps[wave][r16][ks * 32 + kq * 8];
#pragma unroll
            for (int nt = 0; nt < 4; ++nt) {
                const bf16x8 vf = *(const bf16x8*)&Vs[nt * 16 + r16][ks * 32 + kq * 8];
                o[nt] = MFMA16(vf, pf, o[nt], 0, 0, 0);
            }
        }
    }

    // cross-quad l reduction (once per block), then store
    lpart += __shfl_xor(lpart, 16);
    lpart += __shfl_xor(lpart, 32);
    const float inv = 1.0f / lpart;
    const size_t row = q0 + qloc;
#pragma unroll
    for (int nt = 0; nt < 4; ++nt) {
        uint2 pk;
        pk.x = (u32)f2b(o[nt][0] * inv) | ((u32)f2b(o[nt][1] * inv) << 16);
        pk.y = (u32)f2b(o[nt][2] * inv) | ((u32)f2b(o[nt][3] * inv) << 16);
        *(uint2*)&ctx[row * D_MODEL + h * DK + nt * 16 + kq * 4] = pk;
    }
}

// ---------------------------------------------------------------------------
extern "C" void kernel_launch(void* const* d_in, const int* in_sizes, int n_in,
                              void* d_out, int out_size, void* d_ws, size_t ws_size,
                              hipStream_t stream) {
    const float* x    = (const float*)d_in[0];
    const float* fcos = (const float*)d_in[1];
    const float* fsin = (const float*)d_in[2];
    const float* Wq = (const float*)d_in[4];
    const float* Wk = (const float*)d_in[5];
    const float* Wv = (const float*)d_in[6];
    const float* Wo = (const float*)d_in[7];
    const float* ln1 = (const float*)d_in[8];
    const float* ln2 = (const float*)d_in[9];
    const float* w1 = (const float*)d_in[10];
    const float* w2 = (const float*)d_in[11];
    const float* w3 = (const float*)d_in[12];
    float* out = (float*)d_out;

    char* ws = (char*)d_ws;
    size_t off = 0;
    auto alloc = [&](size_t bytes) -> char* {
        char* p = ws + off;
        off += (bytes + 255) & ~(size_t)255;
        return p;
    };
    u16* hb    = (u16*)alloc((size_t)S_LEN * D_MODEL * 2);
    u16* wqkvt = (u16*)alloc((size_t)QKV_LD * D_MODEL * 2);  // [3072][1024]
    u16* wot   = (u16*)alloc((size_t)D_MODEL * D_MODEL * 2);
    u16* qkvb  = (u16*)alloc((size_t)S_LEN * QKV_LD * 2);    // [4096][3072]
    u16* vt    = (u16*)alloc((size_t)S_LEN * D_MODEL * 2);   // [H][DK][S]
    u16* kpack = (u16*)alloc((size_t)S_LEN * D_MODEL * 2);   // [H][S][DK]
    u16* ctxb  = (u16*)alloc((size_t)S_LEN * D_MODEL * 2);
    float* x2  = (float*)alloc((size_t)S_LEN * D_MODEL * 4);
    u16* h2b   = (u16*)alloc((size_t)S_LEN * D_MODEL * 2);
    u16* w1t   = (u16*)alloc((size_t)HIDP * D_MODEL * 2);    // [2816][1024]
    u16* w3t   = (u16*)alloc((size_t)HIDP * D_MODEL * 2);
    u16* w2t   = (u16*)alloc((size_t)D_MODEL * HIDP * 2);    // [1024][2816]
    u16* ffb   = (u16*)alloc((size_t)S_LEN * HIDP * 2);      // [4096][2816]

    const dim3 tb32(32, 8);

    // weight transposes (fp32 -> bf16, N x K layout); QKV concatenated
    tcast_k<<<dim3(32, 32), tb32, 0, stream>>>(Wq, D_MODEL, D_MODEL, wqkvt, D_MODEL);
    tcast_k<<<dim3(32, 32), tb32, 0, stream>>>(Wk, D_MODEL, D_MODEL,
                                               wqkvt + (size_t)D_MODEL * D_MODEL, D_MODEL);
    tcast_k<<<dim3(32, 32), tb32, 0, stream>>>(Wv, D_MODEL, D_MODEL,
                                               wqkvt + (size_t)2 * D_MODEL * D_MODEL, D_MODEL);
    tcast_k<<<dim3(32, 32), tb32, 0, stream>>>(Wo, D_MODEL, D_MODEL, wot, D_MODEL);
    tcast_k<<<dim3(32, HIDP / 32), tb32, 0, stream>>>(w1, D_MODEL, HID, w1t, D_MODEL);
    tcast_k<<<dim3(32, HIDP / 32), tb32, 0, stream>>>(w3, D_MODEL, HID, w3t, D_MODEL);
    tcast_k<<<dim3(HIDP / 32, 32), tb32, 0, stream>>>(w2, HID, D_MODEL, w2t, HIDP);

    // h = rmsnorm(x, ln1)
    rmsnorm_k<<<S_LEN, 256, 0, stream>>>(x, ln1, hb);

    // QKV = h @ [Wq|Wk|Wv]   (one 4096x3072x1024 GEMM)
    gemm128<0><<<dim3(QKV_LD / 128, S_LEN / 128), 256, 0, stream>>>(
        hb, D_MODEL, wqkvt, D_MODEL, qkvb, QKV_LD, D_MODEL, nullptr);

    // RoPE on Q,K halves (Q pre-scaled by 0.125*log2e)
    rope_k<<<(S_LEN * NHEAD * 32) / 256, 256, 0, stream>>>(qkvb, fcos, fsin);

    // K packed + V transposed per head
    packkv_k<<<dim3(S_LEN / 32, DK / 32, NHEAD), tb32, 0, stream>>>(qkvb, vt, kpack);

    // flash attention (1024 blocks, balanced qi mapping)
    flash_k<<<dim3(NHEAD, 64), 256, 0, stream>>>(qkvb, vt, kpack, ctxb);

    // x2 = x + ctx @ Wo
    gemm128<2><<<dim3(D_MODEL / 128, S_LEN / 128), 256, 0, stream>>>(
        ctxb, D_MODEL, wot, D_MODEL, x2, D_MODEL, D_MODEL, x);

    // h2 = rmsnorm(x2, ln2)
    rmsnorm_k<<<S_LEN, 256, 0, stream>>>(x2, ln2, h2b);

    // ff = silu(h2@w1) * (h2@w3)
    gemm_dual64<<<dim3(HIDP / 64, S_LEN / 128), 256, 0, stream>>>(
        h2b, D_MODEL, w1t, w3t, D_MODEL, ffb, HIDP, D_MODEL);

    // out = x2 + ff @ w2
    gemm128<2><<<dim3(D_MODEL / 128, S_LEN / 128), 256, 0, stream>>>(
        ffb, HIDP, w2t, HIDP, out, D_MODEL, HIDP, x2);
}

// Round 8
// 452.030 us; speedup vs baseline: 1.2473x; 1.1191x over previous
//
#include <hip/hip_runtime.h>

#define S_LEN 4096
#define D_MODEL 1024
#define NHEAD 16
#define DK 64
#define HID 2730
#define HIDP 2816
#define QKV_LD 3072

typedef unsigned short u16;
typedef unsigned int u32;
typedef __bf16 bf16x8 __attribute__((ext_vector_type(8)));
typedef float f32x4 __attribute__((ext_vector_type(4)));

#define MFMA16 __builtin_amdgcn_mfma_f32_16x16x32_bf16

__device__ __forceinline__ float b2f(u16 u) {
    return __builtin_bit_cast(float, (u32)u << 16);
}
__device__ __forceinline__ u16 f2b(float f) {
    u32 u = __builtin_bit_cast(u32, f);
    u += 0x7FFF + ((u >> 16) & 1);
    return (u16)(u >> 16);
}
// pack two f32 -> two bf16 (truncate) in one v_perm_b32
__device__ __forceinline__ u32 pk_trunc(float lo, float hi) {
    return __builtin_amdgcn_perm(__builtin_bit_cast(u32, hi),
                                 __builtin_bit_cast(u32, lo), 0x07060302u);
}
// async global->LDS, 16B per lane; dest must be wave-uniform base + lane*16
__device__ __forceinline__ void gll16(const u16* g, u16* l) {
    __builtin_amdgcn_global_load_lds(
        (__attribute__((address_space(1))) void*)(g),
        (__attribute__((address_space(3))) void*)(l),
        16, 0, 0);
}

// ---------------------------------------------------------------------------
// RMSNorm: one block per row (D=1024), fp32 in -> bf16 out
// ---------------------------------------------------------------------------
__global__ __launch_bounds__(256)
void rmsnorm_k(const float* __restrict__ x, const float* __restrict__ w,
               u16* __restrict__ out) {
    const int row = blockIdx.x;
    const int tid = threadIdx.x;
    const float4 v = ((const float4*)(x + (size_t)row * D_MODEL))[tid];
    float ss = v.x * v.x + v.y * v.y + v.z * v.z + v.w * v.w;
    for (int o = 32; o; o >>= 1) ss += __shfl_down(ss, o);
    __shared__ float red[4];
    if ((tid & 63) == 0) red[tid >> 6] = ss;
    __syncthreads();
    const float tot = red[0] + red[1] + red[2] + red[3];
    const float rs = rsqrtf(tot * (1.0f / D_MODEL) + 1e-6f);
    const float4 wv = ((const float4*)w)[tid];
    u16* op = out + (size_t)row * D_MODEL + tid * 4;
    u32 p0 = (u32)f2b(v.x * rs * wv.x) | ((u32)f2b(v.y * rs * wv.y) << 16);
    u32 p1 = (u32)f2b(v.z * rs * wv.z) | ((u32)f2b(v.w * rs * wv.w) << 16);
    uint2 pk; pk.x = p0; pk.y = p1;
    *(uint2*)op = pk;
}

// ---------------------------------------------------------------------------
// Tiled transpose + cast fp32 -> bf16.  out[r][c] = in[c][r], zero-padded.
// ---------------------------------------------------------------------------
__global__ __launch_bounds__(256)
void tcast_k(const float* __restrict__ in, int R, int C,
             u16* __restrict__ out, int outC) {
    __shared__ float t[32][33];
    const int r0 = blockIdx.y * 32;
    const int c0 = blockIdx.x * 32;
    const int tx = threadIdx.x, ty = threadIdx.y;
#pragma unroll
    for (int j = 0; j < 4; ++j) {
        int ir = c0 + ty + j * 8;
        int ic = r0 + tx;
        t[ty + j * 8][tx] = (ir < R && ic < C) ? in[(size_t)ir * C + ic] : 0.0f;
    }
    __syncthreads();
#pragma unroll
    for (int j = 0; j < 4; ++j)
        out[(size_t)(r0 + ty + j * 8) * outC + c0 + tx] = f2b(t[tx][ty + j * 8]);
}

// ---------------------------------------------------------------------------
// Pack K/V per head: kp[h][s][d] = qkv[s][1024 + h*64 + d]   (copy)
//                    vt[h][d][s] = qkv[s][2048 + h*64 + d]   (transpose)
// ---------------------------------------------------------------------------
__global__ __launch_bounds__(256)
void packkv_k(const u16* __restrict__ qkv, u16* __restrict__ vt,
              u16* __restrict__ kp) {
    __shared__ u16 t[32][33];
    const int h = blockIdx.z;
    const int t0 = blockIdx.x * 32;
    const int d0 = blockIdx.y * 32;
    const int tx = threadIdx.x, ty = threadIdx.y;
#pragma unroll
    for (int j = 0; j < 4; ++j) {
        const int s = t0 + ty + j * 8;
        t[ty + j * 8][tx] = qkv[(size_t)s * QKV_LD + 2 * D_MODEL + h * DK + d0 + tx];
        kp[((size_t)h * S_LEN + s) * DK + d0 + tx] =
            qkv[(size_t)s * QKV_LD + D_MODEL + h * DK + d0 + tx];
    }
    __syncthreads();
#pragma unroll
    for (int j = 0; j < 4; ++j)
        vt[(size_t)h * DK * S_LEN + (size_t)(d0 + ty + j * 8) * S_LEN + t0 + tx] =
            t[tx][ty + j * 8];
}

// ---------------------------------------------------------------------------
// RoPE in place; Q additionally scaled by 0.125*log2(e) (Q only feeds QK^T,
// letting flash_k run exp2-space softmax with no per-score scale).
// ---------------------------------------------------------------------------
__global__ __launch_bounds__(256)
void rope_k(u16* __restrict__ qkv, const float* __restrict__ fc,
            const float* __restrict__ fs) {
    const int idx = blockIdx.x * 256 + threadIdx.x;   // S*H*32 total
    const int s = idx >> 9;
    const int rem = idx & 511;
    const int h = rem >> 5;
    const int i = rem & 31;
    const size_t base = (size_t)s * QKV_LD + h * DK + 2 * i;
    const float c = fc[s * 32 + i], sn = fs[s * 32 + i];
    const float SC = 0.125f * 1.44269504f;
    u16* q = qkv + base;
    u16* k = qkv + base + D_MODEL;
    float t0 = b2f(q[0]), t1 = b2f(q[1]);
    q[0] = f2b((t0 * c - t1 * sn) * SC);
    q[1] = f2b((t0 * sn + t1 * c) * SC);
    t0 = b2f(k[0]); t1 = b2f(k[1]);
    k[0] = f2b(t0 * c - t1 * sn);
    k[1] = f2b(t0 * sn + t1 * c);
}

// ---------------------------------------------------------------------------
// 128x128 GEMM (m97 structure): C = A @ Bt^T, global_load_lds staging.
// ---------------------------------------------------------------------------
template <int EPI>
__global__ __launch_bounds__(256)
void gemm128(const u16* __restrict__ A, int lda, const u16* __restrict__ Bt, int ldb,
             void* __restrict__ C, int ldc, int K, const float* __restrict__ resid) {
    const int m0 = blockIdx.y * 128, n0 = blockIdx.x * 128;
    const int tid = threadIdx.x;
    const int wave = tid >> 6, lane = tid & 63;
    const int wr = wave >> 1, wc = wave & 1;
    const int r16 = lane & 15, kq = lane >> 4;

    __shared__ __align__(16) u16 As[128 * 32];
    __shared__ __align__(16) u16 Bs[128 * 32];

    const int srow = tid >> 2, sk = (tid & 3) * 8;
    const u16* ag0 = A + (size_t)(m0 + srow) * lda + sk;
    const u16* ag1 = A + (size_t)(m0 + 64 + srow) * lda + sk;
    const u16* bg0 = Bt + (size_t)(n0 + srow) * ldb + sk;
    const u16* bg1 = Bt + (size_t)(n0 + 64 + srow) * ldb + sk;
    u16* asw = As + wave * 512;
    u16* bsw = Bs + wave * 512;

    f32x4 acc[16];
#pragma unroll
    for (int i = 0; i < 16; ++i) acc[i] = f32x4{0.f, 0.f, 0.f, 0.f};

    for (int k0 = 0; k0 < K; k0 += 32) {
        __syncthreads();
        gll16(ag0 + k0, asw);
        gll16(ag1 + k0, asw + 2048);
        gll16(bg0 + k0, bsw);
        gll16(bg1 + k0, bsw + 2048);
        __syncthreads();
        bf16x8 af[4], bf[4];
#pragma unroll
        for (int mt = 0; mt < 4; ++mt)
            af[mt] = *(const bf16x8*)&As[(wr * 64 + mt * 16 + r16) * 32 + kq * 8];
#pragma unroll
        for (int nt = 0; nt < 4; ++nt)
            bf[nt] = *(const bf16x8*)&Bs[(wc * 64 + nt * 16 + r16) * 32 + kq * 8];
#pragma unroll
        for (int mt = 0; mt < 4; ++mt)
#pragma unroll
            for (int nt = 0; nt < 4; ++nt)
                acc[mt * 4 + nt] = MFMA16(af[mt], bf[nt], acc[mt * 4 + nt], 0, 0, 0);
    }

#pragma unroll
    for (int mt = 0; mt < 4; ++mt) {
#pragma unroll
        for (int nt = 0; nt < 4; ++nt) {
            const int col = n0 + wc * 64 + nt * 16 + r16;
#pragma unroll
            for (int j = 0; j < 4; ++j) {
                const int row = m0 + wr * 64 + mt * 16 + kq * 4 + j;
                if (EPI == 0) {
                    ((u16*)C)[(size_t)row * ldc + col] = f2b(acc[mt * 4 + nt][j]);
                } else {
                    ((float*)C)[(size_t)row * ldc + col] =
                        resid[(size_t)row * ldc + col] + acc[mt * 4 + nt][j];
                }
            }
        }
    }
}

// ---------------------------------------------------------------------------
// 128(M) x 64(N) GEMM + fp32 residual epilogue. 512 blocks for N=1024
// (2 blocks/CU vs 1 for the 128x128 tile). Wave owns 32 rows x 64 cols.
// ---------------------------------------------------------------------------
__global__ __launch_bounds__(256)
void gemm64r(const u16* __restrict__ A, int lda, const u16* __restrict__ Bt, int ldb,
             float* __restrict__ C, int ldc, int K, const float* __restrict__ resid) {
    const int m0 = blockIdx.y * 128, n0 = blockIdx.x * 64;
    const int tid = threadIdx.x;
    const int wave = tid >> 6, lane = tid & 63;
    const int r16 = lane & 15, kq = lane >> 4;

    __shared__ __align__(16) u16 As[128 * 32];
    __shared__ __align__(16) u16 Bs[64 * 32];

    const int srow = tid >> 2, sk = (tid & 3) * 8;
    const u16* ag0 = A + (size_t)(m0 + srow) * lda + sk;
    const u16* ag1 = A + (size_t)(m0 + 64 + srow) * lda + sk;
    const u16* bg = Bt + (size_t)(n0 + srow) * ldb + sk;
    u16* asw = As + wave * 512;
    u16* bsw = Bs + wave * 512;

    f32x4 acc[8];
#pragma unroll
    for (int i = 0; i < 8; ++i) acc[i] = f32x4{0.f, 0.f, 0.f, 0.f};

    for (int k0 = 0; k0 < K; k0 += 32) {
        __syncthreads();
        gll16(ag0 + k0, asw);
        gll16(ag1 + k0, asw + 2048);
        gll16(bg + k0, bsw);
        __syncthreads();
        bf16x8 af[2], bf[4];
#pragma unroll
        for (int mt = 0; mt < 2; ++mt)
            af[mt] = *(const bf16x8*)&As[(wave * 32 + mt * 16 + r16) * 32 + kq * 8];
#pragma unroll
        for (int nt = 0; nt < 4; ++nt)
            bf[nt] = *(const bf16x8*)&Bs[(nt * 16 + r16) * 32 + kq * 8];
#pragma unroll
        for (int mt = 0; mt < 2; ++mt)
#pragma unroll
            for (int nt = 0; nt < 4; ++nt)
                acc[mt * 4 + nt] = MFMA16(af[mt], bf[nt], acc[mt * 4 + nt], 0, 0, 0);
    }

#pragma unroll
    for (int mt = 0; mt < 2; ++mt)
#pragma unroll
        for (int nt = 0; nt < 4; ++nt) {
            const int col = n0 + nt * 16 + r16;
#pragma unroll
            for (int j = 0; j < 4; ++j) {
                const int row = m0 + wave * 32 + mt * 16 + kq * 4 + j;
                C[(size_t)row * ldc + col] =
                    resid[(size_t)row * ldc + col] + acc[mt * 4 + nt][j];
            }
        }
}

// ---------------------------------------------------------------------------
// FFN dual GEMM: tile 128(M) x 64(N per matrix); ff = silu(A@B1^T)*(A@B3^T)
// ---------------------------------------------------------------------------
__global__ __launch_bounds__(256)
void gemm_dual64(const u16* __restrict__ A, int lda,
                 const u16* __restrict__ B1, const u16* __restrict__ B3, int ldb,
                 u16* __restrict__ C, int ldc, int K) {
    const int m0 = blockIdx.y * 128, n0 = blockIdx.x * 64;
    const int tid = threadIdx.x;
    const int wave = tid >> 6, lane = tid & 63;
    const int r16 = lane & 15, kq = lane >> 4;

    __shared__ __align__(16) u16 As[128 * 32];
    __shared__ __align__(16) u16 B1s[64 * 32];
    __shared__ __align__(16) u16 B3s[64 * 32];

    const int srow = tid >> 2, sk = (tid & 3) * 8;
    const u16* ag0 = A + (size_t)(m0 + srow) * lda + sk;
    const u16* ag1 = A + (size_t)(m0 + 64 + srow) * lda + sk;
    const u16* b1g = B1 + (size_t)(n0 + srow) * ldb + sk;
    const u16* b3g = B3 + (size_t)(n0 + srow) * ldb + sk;
    u16* asw = As + wave * 512;
    u16* b1w = B1s + wave * 512;
    u16* b3w = B3s + wave * 512;

    f32x4 acc1[8], acc3[8];
#pragma unroll
    for (int i = 0; i < 8; ++i) {
        acc1[i] = f32x4{0.f, 0.f, 0.f, 0.f};
        acc3[i] = f32x4{0.f, 0.f, 0.f, 0.f};
    }

    for (int k0 = 0; k0 < K; k0 += 32) {
        __syncthreads();
        gll16(ag0 + k0, asw);
        gll16(ag1 + k0, asw + 2048);
        gll16(b1g + k0, b1w);
        gll16(b3g + k0, b3w);
        __syncthreads();
        bf16x8 af[2], b1f[4], b3f[4];
#pragma unroll
        for (int mt = 0; mt < 2; ++mt)
            af[mt] = *(const bf16x8*)&As[(wave * 32 + mt * 16 + r16) * 32 + kq * 8];
#pragma unroll
        for (int nt = 0; nt < 4; ++nt) {
            b1f[nt] = *(const bf16x8*)&B1s[(nt * 16 + r16) * 32 + kq * 8];
            b3f[nt] = *(const bf16x8*)&B3s[(nt * 16 + r16) * 32 + kq * 8];
        }
#pragma unroll
        for (int mt = 0; mt < 2; ++mt)
#pragma unroll
            for (int nt = 0; nt < 4; ++nt) {
                acc1[mt * 4 + nt] = MFMA16(af[mt], b1f[nt], acc1[mt * 4 + nt], 0, 0, 0);
                acc3[mt * 4 + nt] = MFMA16(af[mt], b3f[nt], acc3[mt * 4 + nt], 0, 0, 0);
            }
    }

#pragma unroll
    for (int mt = 0; mt < 2; ++mt)
#pragma unroll
        for (int nt = 0; nt < 4; ++nt) {
            const int col = n0 + nt * 16 + r16;
#pragma unroll
            for (int j = 0; j < 4; ++j) {
                const int row = m0 + wave * 32 + mt * 16 + kq * 4 + j;
                const float v1 = acc1[mt * 4 + nt][j];
                const float v3 = acc3[mt * 4 + nt][j];
                const float sig = 1.0f / (1.0f + __expf(-v1));
                C[(size_t)row * ldc + col] = f2b(v1 * sig * v3);
            }
        }
}

// ---------------------------------------------------------------------------
// Flash attention v4: S^T form, no online max, XOR-swizzled K/V LDS layout
// (conflict-free staging writes + 2-way-free fragment reads), async
// global_load_lds staging (source column permuted; dest lane-linear).
// Physical 16B-chunk index = logical ^ (row & 7); row stride 64 u16.
// ---------------------------------------------------------------------------
__global__ __launch_bounds__(256)
void flash_k(const u16* __restrict__ qkv, const u16* __restrict__ vt,
             const u16* __restrict__ kp, u16* __restrict__ ctx) {
    const int h = blockIdx.x;
    const int by = blockIdx.y;
    const int hi = by >> 4, lo = by & 15;
    const int base = lo + ((hi >> 1) << 4);
    const int qi = (hi & 1) ? (63 - base) : base;
    const int q0 = qi * 64;
    const int tid = threadIdx.x;
    const int wave = tid >> 6, lane = tid & 63;
    const int r16 = lane & 15, kq = lane >> 4;

    __shared__ __align__(16) u16 Ks[64 * 64];   // [kv][dk], chunk-swizzled
    __shared__ __align__(16) u16 Vs[64 * 64];   // [dk][kv], chunk-swizzled
    __shared__ __align__(16) u16 Ps[4][16][72]; // per-wave [q][kv]

    const u16* kb = kp + (size_t)h * S_LEN * DK;
    const u16* vbase = vt + (size_t)h * DK * S_LEN;
    const int srow = tid >> 3;                 // staging row 0..31
    const int lcol = ((tid & 7) ^ (srow & 7)) * 8;  // permuted source col
    const int qloc = wave * 16 + r16;
    const int sw = r16 & 7;                    // read-side swizzle

    const u16* qrow = qkv + (size_t)(q0 + qloc) * QKV_LD + h * DK;
    const bf16x8 qf0 = *(const bf16x8*)(qrow + kq * 8);
    const bf16x8 qf1 = *(const bf16x8*)(qrow + 32 + kq * 8);

    f32x4 o[4];
#pragma unroll
    for (int i = 0; i < 4; ++i) o[i] = f32x4{0.f, 0.f, 0.f, 0.f};
    float lpart = 0.f;

    const int c0 = (kq ^ sw) * 8;          // phys col, logical chunk kq
    const int c1 = ((4 ^ kq) ^ sw) * 8;    // phys col, logical chunk 4+kq

    for (int t = 0; t <= qi; ++t) {
        const int t0 = t * 64;
        __syncthreads();
#pragma unroll
        for (int i = 0; i < 2; ++i) {
            const int r = srow + i * 32;
            gll16(kb + (size_t)(t0 + r) * DK + lcol, Ks + tid * 8 + i * 2048);
            gll16(vbase + (size_t)r * S_LEN + t0 + lcol, Vs + tid * 8 + i * 2048);
        }
        __syncthreads();

        // S^T[kv][q] = K·Q^T (Q pre-scaled): col=q=r16 per lane
        f32x4 s[4];
#pragma unroll
        for (int nt = 0; nt < 4; ++nt) {
            s[nt] = f32x4{0.f, 0.f, 0.f, 0.f};
            const bf16x8 k0 = *(const bf16x8*)&Ks[(nt * 16 + r16) * 64 + c0];
            s[nt] = MFMA16(k0, qf0, s[nt], 0, 0, 0);
            const bf16x8 k1 = *(const bf16x8*)&Ks[(nt * 16 + r16) * 64 + c1];
            s[nt] = MFMA16(k1, qf1, s[nt], 0, 0, 0);
        }

        // p = 2^s, diag-masked to 0; accumulate per-lane l partial
        float p[16];
#pragma unroll
        for (int nt = 0; nt < 4; ++nt)
#pragma unroll
            for (int j = 0; j < 4; ++j) p[nt * 4 + j] = exp2f(s[nt][j]);
        if (t == qi) {
#pragma unroll
            for (int nt = 0; nt < 4; ++nt)
#pragma unroll
                for (int j = 0; j < 4; ++j)
                    if ((nt * 16 + kq * 4 + j) > qloc) p[nt * 4 + j] = 0.f;
        }
#pragma unroll
        for (int i = 0; i < 16; ++i) lpart += p[i];

        // P^T -> wave-private LDS [q][kv], truncating bf16 pack
#pragma unroll
        for (int nt = 0; nt < 4; ++nt) {
            uint2 pk;
            pk.x = pk_trunc(p[nt * 4 + 0], p[nt * 4 + 1]);
            pk.y = pk_trunc(p[nt * 4 + 2], p[nt * 4 + 3]);
            *(uint2*)&Ps[wave][r16][nt * 16 + kq * 4] = pk;
        }

        // O^T += V^T @ P^T
#pragma unroll
        for (int ks = 0; ks < 2; ++ks) {
            const bf16x8 pf = *(const bf16x8*)&Ps[wave][r16][ks * 32 + kq * 8];
            const int cv = (((ks << 2) ^ kq) ^ sw) * 8;   // logical chunk ks*4+kq
#pragma unroll
            for (int nt = 0; nt < 4; ++nt) {
                const bf16x8 vf = *(const bf16x8*)&Vs[(nt * 16 + r16) * 64 + cv];
                o[nt] = MFMA16(vf, pf, o[nt], 0, 0, 0);
            }
        }
    }

    // cross-quad l reduction (once per block), then store
    lpart += __shfl_xor(lpart, 16);
    lpart += __shfl_xor(lpart, 32);
    const float inv = 1.0f / lpart;
    const size_t row = q0 + qloc;
#pragma unroll
    for (int nt = 0; nt < 4; ++nt) {
        uint2 pk;
        pk.x = (u32)f2b(o[nt][0] * inv) | ((u32)f2b(o[nt][1] * inv) << 16);
        pk.y = (u32)f2b(o[nt][2] * inv) | ((u32)f2b(o[nt][3] * inv) << 16);
        *(uint2*)&ctx[row * D_MODEL + h * DK + nt * 16 + kq * 4] = pk;
    }
}

// ---------------------------------------------------------------------------
extern "C" void kernel_launch(void* const* d_in, const int* in_sizes, int n_in,
                              void* d_out, int out_size, void* d_ws, size_t ws_size,
                              hipStream_t stream) {
    const float* x    = (const float*)d_in[0];
    const float* fcos = (const float*)d_in[1];
    const float* fsin = (const float*)d_in[2];
    const float* Wq = (const float*)d_in[4];
    const float* Wk = (const float*)d_in[5];
    const float* Wv = (const float*)d_in[6];
    const float* Wo = (const float*)d_in[7];
    const float* ln1 = (const float*)d_in[8];
    const float* ln2 = (const float*)d_in[9];
    const float* w1 = (const float*)d_in[10];
    const float* w2 = (const float*)d_in[11];
    const float* w3 = (const float*)d_in[12];
    float* out = (float*)d_out;

    char* ws = (char*)d_ws;
    size_t off = 0;
    auto alloc = [&](size_t bytes) -> char* {
        char* p = ws + off;
        off += (bytes + 255) & ~(size_t)255;
        return p;
    };
    u16* hb    = (u16*)alloc((size_t)S_LEN * D_MODEL * 2);
    u16* wqkvt = (u16*)alloc((size_t)QKV_LD * D_MODEL * 2);  // [3072][1024]
    u16* wot   = (u16*)alloc((size_t)D_MODEL * D_MODEL * 2);
    u16* qkvb  = (u16*)alloc((size_t)S_LEN * QKV_LD * 2);    // [4096][3072]
    u16* vt    = (u16*)alloc((size_t)S_LEN * D_MODEL * 2);   // [H][DK][S]
    u16* kpack = (u16*)alloc((size_t)S_LEN * D_MODEL * 2);   // [H][S][DK]
    u16* ctxb  = (u16*)alloc((size_t)S_LEN * D_MODEL * 2);
    float* x2  = (float*)alloc((size_t)S_LEN * D_MODEL * 4);
    u16* h2b   = (u16*)alloc((size_t)S_LEN * D_MODEL * 2);
    u16* w1t   = (u16*)alloc((size_t)HIDP * D_MODEL * 2);    // [2816][1024]
    u16* w3t   = (u16*)alloc((size_t)HIDP * D_MODEL * 2);
    u16* w2t   = (u16*)alloc((size_t)D_MODEL * HIDP * 2);    // [1024][2816]
    u16* ffb   = (u16*)alloc((size_t)S_LEN * HIDP * 2);      // [4096][2816]

    const dim3 tb32(32, 8);

    // weight transposes (fp32 -> bf16, N x K layout); QKV concatenated
    tcast_k<<<dim3(32, 32), tb32, 0, stream>>>(Wq, D_MODEL, D_MODEL, wqkvt, D_MODEL);
    tcast_k<<<dim3(32, 32), tb32, 0, stream>>>(Wk, D_MODEL, D_MODEL,
                                               wqkvt + (size_t)D_MODEL * D_MODEL, D_MODEL);
    tcast_k<<<dim3(32, 32), tb32, 0, stream>>>(Wv, D_MODEL, D_MODEL,
                                               wqkvt + (size_t)2 * D_MODEL * D_MODEL, D_MODEL);
    tcast_k<<<dim3(32, 32), tb32, 0, stream>>>(Wo, D_MODEL, D_MODEL, wot, D_MODEL);
    tcast_k<<<dim3(32, HIDP / 32), tb32, 0, stream>>>(w1, D_MODEL, HID, w1t, D_MODEL);
    tcast_k<<<dim3(32, HIDP / 32), tb32, 0, stream>>>(w3, D_MODEL, HID, w3t, D_MODEL);
    tcast_k<<<dim3(HIDP / 32, 32), tb32, 0, stream>>>(w2, HID, D_MODEL, w2t, HIDP);

    // h = rmsnorm(x, ln1)
    rmsnorm_k<<<S_LEN, 256, 0, stream>>>(x, ln1, hb);

    // QKV = h @ [Wq|Wk|Wv]   (one 4096x3072x1024 GEMM)
    gemm128<0><<<dim3(QKV_LD / 128, S_LEN / 128), 256, 0, stream>>>(
        hb, D_MODEL, wqkvt, D_MODEL, qkvb, QKV_LD, D_MODEL, nullptr);

    // RoPE on Q,K halves (Q pre-scaled by 0.125*log2e)
    rope_k<<<(S_LEN * NHEAD * 32) / 256, 256, 0, stream>>>(qkvb, fcos, fsin);

    // K packed + V transposed per head
    packkv_k<<<dim3(S_LEN / 32, DK / 32, NHEAD), tb32, 0, stream>>>(qkvb, vt, kpack);

    // flash attention (1024 blocks, balanced qi mapping)
    flash_k<<<dim3(NHEAD, 64), 256, 0, stream>>>(qkvb, vt, kpack, ctxb);

    // x2 = x + ctx @ Wo   (128x64 tile -> 512 blocks, 2/CU)
    gemm64r<<<dim3(D_MODEL / 64, S_LEN / 128), 256, 0, stream>>>(
        ctxb, D_MODEL, wot, D_MODEL, x2, D_MODEL, D_MODEL, x);

    // h2 = rmsnorm(x2, ln2)
    rmsnorm_k<<<S_LEN, 256, 0, stream>>>(x2, ln2, h2b);

    // ff = silu(h2@w1) * (h2@w3)
    gemm_dual64<<<dim3(HIDP / 64, S_LEN / 128), 256, 0, stream>>>(
        h2b, D_MODEL, w1t, w3t, D_MODEL, ffb, HIDP, D_MODEL);

    // out = x2 + ff @ w2  (128x64 tile -> 512 blocks)
    gemm64r<<<dim3(D_MODEL / 64, S_LEN / 128), 256, 0, stream>>>(
        ffb, HIDP, w2t, HIDP, out, D_MODEL, HIDP, x2);
}

// Round 9
// 424.162 us; speedup vs baseline: 1.3293x; 1.0657x over previous
//
#include <hip/hip_runtime.h>

#define S_LEN 4096
#define D_MODEL 1024
#define NHEAD 16
#define DK 64
#define HID 2730
#define HIDP 2816
#define QKV_LD 3072

typedef unsigned short u16;
typedef unsigned int u32;
typedef __bf16 bf16x8 __attribute__((ext_vector_type(8)));
typedef float f32x4 __attribute__((ext_vector_type(4)));

#define MFMA16 __builtin_amdgcn_mfma_f32_16x16x32_bf16

__device__ __forceinline__ float b2f(u16 u) {
    return __builtin_bit_cast(float, (u32)u << 16);
}
__device__ __forceinline__ u16 f2b(float f) {
    u32 u = __builtin_bit_cast(u32, f);
    u += 0x7FFF + ((u >> 16) & 1);
    return (u16)(u >> 16);
}
// pack two f32 -> two bf16 (truncate) in one v_perm_b32
__device__ __forceinline__ u32 pk_trunc(float lo, float hi) {
    return __builtin_amdgcn_perm(__builtin_bit_cast(u32, hi),
                                 __builtin_bit_cast(u32, lo), 0x07060302u);
}
// async global->LDS, 16B per lane; dest must be wave-uniform base + lane*16
__device__ __forceinline__ void gll16(const u16* g, u16* l) {
    __builtin_amdgcn_global_load_lds(
        (__attribute__((address_space(1))) void*)(g),
        (__attribute__((address_space(3))) void*)(l),
        16, 0, 0);
}

// ---------------------------------------------------------------------------
// RMSNorm: one block per row (D=1024), fp32 in -> bf16 out
// ---------------------------------------------------------------------------
__global__ __launch_bounds__(256)
void rmsnorm_k(const float* __restrict__ x, const float* __restrict__ w,
               u16* __restrict__ out) {
    const int row = blockIdx.x;
    const int tid = threadIdx.x;
    const float4 v = ((const float4*)(x + (size_t)row * D_MODEL))[tid];
    float ss = v.x * v.x + v.y * v.y + v.z * v.z + v.w * v.w;
    for (int o = 32; o; o >>= 1) ss += __shfl_down(ss, o);
    __shared__ float red[4];
    if ((tid & 63) == 0) red[tid >> 6] = ss;
    __syncthreads();
    const float tot = red[0] + red[1] + red[2] + red[3];
    const float rs = rsqrtf(tot * (1.0f / D_MODEL) + 1e-6f);
    const float4 wv = ((const float4*)w)[tid];
    u16* op = out + (size_t)row * D_MODEL + tid * 4;
    u32 p0 = (u32)f2b(v.x * rs * wv.x) | ((u32)f2b(v.y * rs * wv.y) << 16);
    u32 p1 = (u32)f2b(v.z * rs * wv.z) | ((u32)f2b(v.w * rs * wv.w) << 16);
    uint2 pk; pk.x = p0; pk.y = p1;
    *(uint2*)op = pk;
}

// ---------------------------------------------------------------------------
// All 7 weight transposes (fp32 -> bf16, out[r][c]=in[c][r], zero-pad) in ONE
// launch. Flat grid; static segment table. Block (32,8).
// segs: 0..3 = Wq,Wk,Wv,Wo (1024 blocks each); 4,5 = w1,w3 (2816); 6 = w2 (2816)
// ---------------------------------------------------------------------------
__global__ __launch_bounds__(256)
void tcast_all(const float* s0, const float* s1, const float* s2,
               const float* s3, const float* s4, const float* s5,
               const float* s6, u16* d0, u16* d1, u16* d2, u16* d3,
               u16* d4, u16* d5, u16* d6) {
    const float* srcs[7] = {s0, s1, s2, s3, s4, s5, s6};
    u16* dsts[7] = {d0, d1, d2, d3, d4, d5, d6};
    const int RR[7] = {1024, 1024, 1024, 1024, 1024, 1024, 2730};
    const int CC[7] = {1024, 1024, 1024, 1024, 2730, 2730, 1024};
    const int OC[7] = {1024, 1024, 1024, 1024, 1024, 1024, 2816};
    const int XD[7] = {32, 32, 32, 32, 32, 32, 88};

    const int bid = blockIdx.x;
    int seg, start;
    if (bid < 4096)      { seg = bid >> 10; start = seg << 10; }
    else if (bid < 6912) { seg = 4; start = 4096; }
    else if (bid < 9728) { seg = 5; start = 6912; }
    else                 { seg = 6; start = 9728; }
    const int local = bid - start;
    const int bx = local % XD[seg], byy = local / XD[seg];
    const float* in = srcs[seg];
    u16* out = dsts[seg];
    const int R = RR[seg], C = CC[seg], outC = OC[seg];

    __shared__ float t[32][33];
    const int r0 = byy * 32;
    const int c0 = bx * 32;
    const int tx = threadIdx.x, ty = threadIdx.y;
#pragma unroll
    for (int j = 0; j < 4; ++j) {
        int ir = c0 + ty + j * 8;
        int ic = r0 + tx;
        t[ty + j * 8][tx] = (ir < R && ic < C) ? in[(size_t)ir * C + ic] : 0.0f;
    }
    __syncthreads();
#pragma unroll
    for (int j = 0; j < 4; ++j)
        out[(size_t)(r0 + ty + j * 8) * outC + c0 + tx] = f2b(t[tx][ty + j * 8]);
}

// ---------------------------------------------------------------------------
// Pack K/V per head, K-RoPE fused:
//   kp[h][s][d] = rope(qkv[s][1024 + h*64 + d])
//   vt[h][d][s] = qkv[s][2048 + h*64 + d]
// grid (S/32, DK/32, H), block (32,8)
// ---------------------------------------------------------------------------
__global__ __launch_bounds__(256)
void packkv_k(const u16* __restrict__ qkv, const float* __restrict__ fc,
              const float* __restrict__ fs, u16* __restrict__ vt,
              u16* __restrict__ kp) {
    __shared__ u16 t[32][33];
    const int h = blockIdx.z;
    const int t0 = blockIdx.x * 32;
    const int d0 = blockIdx.y * 32;
    const int tx = threadIdx.x, ty = threadIdx.y;
#pragma unroll
    for (int j = 0; j < 4; ++j)
        t[ty + j * 8][tx] =
            qkv[(size_t)(t0 + ty + j * 8) * QKV_LD + 2 * D_MODEL + h * DK + d0 + tx];

    // K path: flat id, 4 consecutive d (= 2 rope pairs) per thread
    const int id = ty * 32 + tx;
    const int sA = t0 + (id >> 3);
    const int dA = d0 + (id & 7) * 4;
    uint2 kvp = *(const uint2*)(qkv + (size_t)sA * QKV_LD + D_MODEL + h * DK + dA);
    const int fi = sA * 32 + (dA >> 1);
    const float cc0 = fc[fi], ss0 = fs[fi];
    const float cc1 = fc[fi + 1], ss1 = fs[fi + 1];
    auto rpk = [](u32 w, float c, float s) -> u32 {
        const float a = b2f((u16)w), b = b2f((u16)(w >> 16));
        return (u32)f2b(a * c - b * s) | ((u32)f2b(a * s + b * c) << 16);
    };
    kvp.x = rpk(kvp.x, cc0, ss0);
    kvp.y = rpk(kvp.y, cc1, ss1);
    *(uint2*)(kp + ((size_t)h * S_LEN + sA) * DK + dA) = kvp;

    __syncthreads();
#pragma unroll
    for (int j = 0; j < 4; ++j)
        vt[(size_t)h * DK * S_LEN + (size_t)(d0 + ty + j * 8) * S_LEN + t0 + tx] =
            t[tx][ty + j * 8];
}

// ---------------------------------------------------------------------------
// 128x128 GEMM (m97 structure): C = A @ Bt^T, global_load_lds staging.
// ---------------------------------------------------------------------------
template <int EPI>
__global__ __launch_bounds__(256)
void gemm128(const u16* __restrict__ A, int lda, const u16* __restrict__ Bt, int ldb,
             void* __restrict__ C, int ldc, int K, const float* __restrict__ resid) {
    const int m0 = blockIdx.y * 128, n0 = blockIdx.x * 128;
    const int tid = threadIdx.x;
    const int wave = tid >> 6, lane = tid & 63;
    const int wr = wave >> 1, wc = wave & 1;
    const int r16 = lane & 15, kq = lane >> 4;

    __shared__ __align__(16) u16 As[128 * 32];
    __shared__ __align__(16) u16 Bs[128 * 32];

    const int srow = tid >> 2, sk = (tid & 3) * 8;
    const u16* ag0 = A + (size_t)(m0 + srow) * lda + sk;
    const u16* ag1 = A + (size_t)(m0 + 64 + srow) * lda + sk;
    const u16* bg0 = Bt + (size_t)(n0 + srow) * ldb + sk;
    const u16* bg1 = Bt + (size_t)(n0 + 64 + srow) * ldb + sk;
    u16* asw = As + wave * 512;
    u16* bsw = Bs + wave * 512;

    f32x4 acc[16];
#pragma unroll
    for (int i = 0; i < 16; ++i) acc[i] = f32x4{0.f, 0.f, 0.f, 0.f};

    for (int k0 = 0; k0 < K; k0 += 32) {
        __syncthreads();
        gll16(ag0 + k0, asw);
        gll16(ag1 + k0, asw + 2048);
        gll16(bg0 + k0, bsw);
        gll16(bg1 + k0, bsw + 2048);
        __syncthreads();
        bf16x8 af[4], bf[4];
#pragma unroll
        for (int mt = 0; mt < 4; ++mt)
            af[mt] = *(const bf16x8*)&As[(wr * 64 + mt * 16 + r16) * 32 + kq * 8];
#pragma unroll
        for (int nt = 0; nt < 4; ++nt)
            bf[nt] = *(const bf16x8*)&Bs[(wc * 64 + nt * 16 + r16) * 32 + kq * 8];
#pragma unroll
        for (int mt = 0; mt < 4; ++mt)
#pragma unroll
            for (int nt = 0; nt < 4; ++nt)
                acc[mt * 4 + nt] = MFMA16(af[mt], bf[nt], acc[mt * 4 + nt], 0, 0, 0);
    }

#pragma unroll
    for (int mt = 0; mt < 4; ++mt) {
#pragma unroll
        for (int nt = 0; nt < 4; ++nt) {
            const int col = n0 + wc * 64 + nt * 16 + r16;
#pragma unroll
            for (int j = 0; j < 4; ++j) {
                const int row = m0 + wr * 64 + mt * 16 + kq * 4 + j;
                if (EPI == 0) {
                    ((u16*)C)[(size_t)row * ldc + col] = f2b(acc[mt * 4 + nt][j]);
                } else {
                    ((float*)C)[(size_t)row * ldc + col] =
                        resid[(size_t)row * ldc + col] + acc[mt * 4 + nt][j];
                }
            }
        }
    }
}

// ---------------------------------------------------------------------------
// 128(M) x 64(N) GEMM + fp32 residual epilogue (512 blocks at N=1024).
// ---------------------------------------------------------------------------
__global__ __launch_bounds__(256)
void gemm64r(const u16* __restrict__ A, int lda, const u16* __restrict__ Bt, int ldb,
             float* __restrict__ C, int ldc, int K, const float* __restrict__ resid) {
    const int m0 = blockIdx.y * 128, n0 = blockIdx.x * 64;
    const int tid = threadIdx.x;
    const int wave = tid >> 6, lane = tid & 63;
    const int r16 = lane & 15, kq = lane >> 4;

    __shared__ __align__(16) u16 As[128 * 32];
    __shared__ __align__(16) u16 Bs[64 * 32];

    const int srow = tid >> 2, sk = (tid & 3) * 8;
    const u16* ag0 = A + (size_t)(m0 + srow) * lda + sk;
    const u16* ag1 = A + (size_t)(m0 + 64 + srow) * lda + sk;
    const u16* bg = Bt + (size_t)(n0 + srow) * ldb + sk;
    u16* asw = As + wave * 512;
    u16* bsw = Bs + wave * 512;

    f32x4 acc[8];
#pragma unroll
    for (int i = 0; i < 8; ++i) acc[i] = f32x4{0.f, 0.f, 0.f, 0.f};

    for (int k0 = 0; k0 < K; k0 += 32) {
        __syncthreads();
        gll16(ag0 + k0, asw);
        gll16(ag1 + k0, asw + 2048);
        gll16(bg + k0, bsw);
        __syncthreads();
        bf16x8 af[2], bf[4];
#pragma unroll
        for (int mt = 0; mt < 2; ++mt)
            af[mt] = *(const bf16x8*)&As[(wave * 32 + mt * 16 + r16) * 32 + kq * 8];
#pragma unroll
        for (int nt = 0; nt < 4; ++nt)
            bf[nt] = *(const bf16x8*)&Bs[(nt * 16 + r16) * 32 + kq * 8];
#pragma unroll
        for (int mt = 0; mt < 2; ++mt)
#pragma unroll
            for (int nt = 0; nt < 4; ++nt)
                acc[mt * 4 + nt] = MFMA16(af[mt], bf[nt], acc[mt * 4 + nt], 0, 0, 0);
    }

#pragma unroll
    for (int mt = 0; mt < 2; ++mt)
#pragma unroll
        for (int nt = 0; nt < 4; ++nt) {
            const int col = n0 + nt * 16 + r16;
#pragma unroll
            for (int j = 0; j < 4; ++j) {
                const int row = m0 + wave * 32 + mt * 16 + kq * 4 + j;
                C[(size_t)row * ldc + col] =
                    resid[(size_t)row * ldc + col] + acc[mt * 4 + nt][j];
            }
        }
}

// ---------------------------------------------------------------------------
// FFN dual GEMM: tile 128(M) x 64(N per matrix); ff = silu(A@B1^T)*(A@B3^T)
// ---------------------------------------------------------------------------
__global__ __launch_bounds__(256)
void gemm_dual64(const u16* __restrict__ A, int lda,
                 const u16* __restrict__ B1, const u16* __restrict__ B3, int ldb,
                 u16* __restrict__ C, int ldc, int K) {
    const int m0 = blockIdx.y * 128, n0 = blockIdx.x * 64;
    const int tid = threadIdx.x;
    const int wave = tid >> 6, lane = tid & 63;
    const int r16 = lane & 15, kq = lane >> 4;

    __shared__ __align__(16) u16 As[128 * 32];
    __shared__ __align__(16) u16 B1s[64 * 32];
    __shared__ __align__(16) u16 B3s[64 * 32];

    const int srow = tid >> 2, sk = (tid & 3) * 8;
    const u16* ag0 = A + (size_t)(m0 + srow) * lda + sk;
    const u16* ag1 = A + (size_t)(m0 + 64 + srow) * lda + sk;
    const u16* b1g = B1 + (size_t)(n0 + srow) * ldb + sk;
    const u16* b3g = B3 + (size_t)(n0 + srow) * ldb + sk;
    u16* asw = As + wave * 512;
    u16* b1w = B1s + wave * 512;
    u16* b3w = B3s + wave * 512;

    f32x4 acc1[8], acc3[8];
#pragma unroll
    for (int i = 0; i < 8; ++i) {
        acc1[i] = f32x4{0.f, 0.f, 0.f, 0.f};
        acc3[i] = f32x4{0.f, 0.f, 0.f, 0.f};
    }

    for (int k0 = 0; k0 < K; k0 += 32) {
        __syncthreads();
        gll16(ag0 + k0, asw);
        gll16(ag1 + k0, asw + 2048);
        gll16(b1g + k0, b1w);
        gll16(b3g + k0, b3w);
        __syncthreads();
        bf16x8 af[2], b1f[4], b3f[4];
#pragma unroll
        for (int mt = 0; mt < 2; ++mt)
            af[mt] = *(const bf16x8*)&As[(wave * 32 + mt * 16 + r16) * 32 + kq * 8];
#pragma unroll
        for (int nt = 0; nt < 4; ++nt) {
            b1f[nt] = *(const bf16x8*)&B1s[(nt * 16 + r16) * 32 + kq * 8];
            b3f[nt] = *(const bf16x8*)&B3s[(nt * 16 + r16) * 32 + kq * 8];
        }
#pragma unroll
        for (int mt = 0; mt < 2; ++mt)
#pragma unroll
            for (int nt = 0; nt < 4; ++nt) {
                acc1[mt * 4 + nt] = MFMA16(af[mt], b1f[nt], acc1[mt * 4 + nt], 0, 0, 0);
                acc3[mt * 4 + nt] = MFMA16(af[mt], b3f[nt], acc3[mt * 4 + nt], 0, 0, 0);
            }
    }

#pragma unroll
    for (int mt = 0; mt < 2; ++mt)
#pragma unroll
        for (int nt = 0; nt < 4; ++nt) {
            const int col = n0 + nt * 16 + r16;
#pragma unroll
            for (int j = 0; j < 4; ++j) {
                const int row = m0 + wave * 32 + mt * 16 + kq * 4 + j;
                const float v1 = acc1[mt * 4 + nt][j];
                const float v3 = acc3[mt * 4 + nt][j];
                const float sig = 1.0f / (1.0f + __expf(-v1));
                C[(size_t)row * ldc + col] = f2b(v1 * sig * v3);
            }
        }
}

// ---------------------------------------------------------------------------
// Flash attention v5: 128-wide KV tiles (half the barriers), staged as two
// verified 64x64 XOR-swizzled sub-buffers each for K and V; softmax+PV in two
// 64-halves reusing one wave-private swizzled Ps. Q RoPE+scale fused at load.
// LDS exactly 40960 B -> 4 blocks/CU.
// ---------------------------------------------------------------------------
__global__ __launch_bounds__(256)
void flash_k(const u16* __restrict__ qkv, const u16* __restrict__ vt,
             const u16* __restrict__ kp, const float* __restrict__ fc,
             const float* __restrict__ fs, u16* __restrict__ ctx) {
    const int h = blockIdx.x;
    const int by = blockIdx.y;
    const int hi = by >> 4, lo = by & 15;
    const int base = lo + ((hi >> 1) << 4);
    const int qi = (hi & 1) ? (63 - base) : base;
    const int q0 = qi * 64;
    const int tid = threadIdx.x;
    const int wave = tid >> 6, lane = tid & 63;
    const int r16 = lane & 15, kq = lane >> 4;

    __shared__ __align__(16) u16 KsA[64 * 64];   // kv t0..t0+63
    __shared__ __align__(16) u16 KsB[64 * 64];   // kv t0+64..t0+127
    __shared__ __align__(16) u16 VsA[64 * 64];   // [d][kv lo-half]
    __shared__ __align__(16) u16 VsB[64 * 64];   // [d][kv hi-half]
    __shared__ __align__(16) u16 Ps[4 * 16 * 64]; // per-wave [q][kv], swizzled

    const u16* kb = kp + (size_t)h * S_LEN * DK;
    const u16* vb = vt + (size_t)h * DK * S_LEN;
    const int srow = tid >> 3;
    const int lcol = ((tid & 7) ^ (srow & 7)) * 8;
    const int qloc = wave * 16 + r16;
    const int qglob = q0 + qloc;
    const int sw = r16 & 7;
    const int c0 = (kq ^ sw) * 8;
    const int c1 = ((4 ^ kq) ^ sw) * 8;
    const int psw = r16 & 14;
    u16* psrow = Ps + wave * 1024 + r16 * 64;

    // Q: raw load + RoPE + 0.125*log2e scale, in registers
    const float SC = 0.125f * 1.44269504f;
    const u16* qrow = qkv + (size_t)qglob * QKV_LD + h * DK;
    uint4 uq0 = *(const uint4*)(qrow + kq * 8);
    uint4 uq1 = *(const uint4*)(qrow + 32 + kq * 8);
    const float4 c0v = *(const float4*)(fc + qglob * 32 + kq * 4);
    const float4 s0v = *(const float4*)(fs + qglob * 32 + kq * 4);
    const float4 c1v = *(const float4*)(fc + qglob * 32 + 16 + kq * 4);
    const float4 s1v = *(const float4*)(fs + qglob * 32 + 16 + kq * 4);
    auto rp = [SC](u32 w, float c, float s) -> u32 {
        const float a = b2f((u16)w), b = b2f((u16)(w >> 16));
        return (u32)f2b((a * c - b * s) * SC) |
               ((u32)f2b((a * s + b * c) * SC) << 16);
    };
    uq0.x = rp(uq0.x, c0v.x, s0v.x); uq0.y = rp(uq0.y, c0v.y, s0v.y);
    uq0.z = rp(uq0.z, c0v.z, s0v.z); uq0.w = rp(uq0.w, c0v.w, s0v.w);
    uq1.x = rp(uq1.x, c1v.x, s1v.x); uq1.y = rp(uq1.y, c1v.y, s1v.y);
    uq1.z = rp(uq1.z, c1v.z, s1v.z); uq1.w = rp(uq1.w, c1v.w, s1v.w);
    const bf16x8 qf0 = __builtin_bit_cast(bf16x8, uq0);
    const bf16x8 qf1 = __builtin_bit_cast(bf16x8, uq1);

    f32x4 o[4];
#pragma unroll
    for (int i = 0; i < 4; ++i) o[i] = f32x4{0.f, 0.f, 0.f, 0.f};
    float lpart = 0.f;
    const int T = (qi + 2) >> 1;   // number of 128-kv tiles

    for (int t = 0; t < T; ++t) {
        const int t0 = t * 128;
        __syncthreads();
#pragma unroll
        for (int i = 0; i < 2; ++i) {
            const int r = srow + i * 32;
            gll16(kb + (size_t)(t0 + r) * DK + lcol, KsA + tid * 8 + i * 2048);
            gll16(kb + (size_t)(t0 + 64 + r) * DK + lcol, KsB + tid * 8 + i * 2048);
            gll16(vb + (size_t)r * S_LEN + t0 + lcol, VsA + tid * 8 + i * 2048);
            gll16(vb + (size_t)r * S_LEN + t0 + 64 + lcol, VsB + tid * 8 + i * 2048);
        }
        __syncthreads();

        // S^T[kv][q] over 128 kv: 8 MFMA-tiles
        f32x4 s[8];
#pragma unroll
        for (int nt = 0; nt < 4; ++nt) {
            s[nt] = f32x4{0.f, 0.f, 0.f, 0.f};
            const bf16x8 k0 = *(const bf16x8*)&KsA[(nt * 16 + r16) * 64 + c0];
            s[nt] = MFMA16(k0, qf0, s[nt], 0, 0, 0);
            const bf16x8 k1 = *(const bf16x8*)&KsA[(nt * 16 + r16) * 64 + c1];
            s[nt] = MFMA16(k1, qf1, s[nt], 0, 0, 0);
        }
#pragma unroll
        for (int nt = 0; nt < 4; ++nt) {
            s[4 + nt] = f32x4{0.f, 0.f, 0.f, 0.f};
            const bf16x8 k0 = *(const bf16x8*)&KsB[(nt * 16 + r16) * 64 + c0];
            s[4 + nt] = MFMA16(k0, qf0, s[4 + nt], 0, 0, 0);
            const bf16x8 k1 = *(const bf16x8*)&KsB[(nt * 16 + r16) * 64 + c1];
            s[4 + nt] = MFMA16(k1, qf1, s[4 + nt], 0, 0, 0);
        }

        const bool lastT = (t == T - 1);
#pragma unroll
        for (int p = 0; p < 2; ++p) {
            float pr[16];
#pragma unroll
            for (int nt = 0; nt < 4; ++nt)
#pragma unroll
                for (int j = 0; j < 4; ++j)
                    pr[nt * 4 + j] = exp2f(s[p * 4 + nt][j]);
            if (lastT) {
                const int kvb = t0 + p * 64;
#pragma unroll
                for (int nt = 0; nt < 4; ++nt)
#pragma unroll
                    for (int j = 0; j < 4; ++j)
                        if ((kvb + nt * 16 + kq * 4 + j) > qglob)
                            pr[nt * 4 + j] = 0.f;
            }
#pragma unroll
            for (int i = 0; i < 16; ++i) lpart += pr[i];

            // P^T -> swizzled wave-private Ps [q=r16][kv]
#pragma unroll
            for (int nt = 0; nt < 4; ++nt) {
                uint2 pk;
                pk.x = pk_trunc(pr[nt * 4 + 0], pr[nt * 4 + 1]);
                pk.y = pk_trunc(pr[nt * 4 + 2], pr[nt * 4 + 3]);
                *(uint2*)&psrow[((nt * 4 + kq) ^ psw) * 4] = pk;
            }

            // O^T += V^T @ P^T
#pragma unroll
            for (int ks = 0; ks < 2; ++ks) {
                const bf16x8 pf =
                    *(const bf16x8*)&psrow[((8 * ks + 2 * kq) ^ psw) * 4];
                const int cv = (((ks << 2) ^ kq) ^ sw) * 8;
#pragma unroll
                for (int nt = 0; nt < 4; ++nt) {
                    const bf16x8 vf = p
                        ? *(const bf16x8*)&VsB[(nt * 16 + r16) * 64 + cv]
                        : *(const bf16x8*)&VsA[(nt * 16 + r16) * 64 + cv];
                    o[nt] = MFMA16(vf, pf, o[nt], 0, 0, 0);
                }
            }
        }
    }

    // cross-quad l reduction (once per block), then store
    lpart += __shfl_xor(lpart, 16);
    lpart += __shfl_xor(lpart, 32);
    const float inv = 1.0f / lpart;
    const size_t row = qglob;
#pragma unroll
    for (int nt = 0; nt < 4; ++nt) {
        uint2 pk;
        pk.x = (u32)f2b(o[nt][0] * inv) | ((u32)f2b(o[nt][1] * inv) << 16);
        pk.y = (u32)f2b(o[nt][2] * inv) | ((u32)f2b(o[nt][3] * inv) << 16);
        *(uint2*)&ctx[row * D_MODEL + h * DK + nt * 16 + kq * 4] = pk;
    }
}

// ---------------------------------------------------------------------------
extern "C" void kernel_launch(void* const* d_in, const int* in_sizes, int n_in,
                              void* d_out, int out_size, void* d_ws, size_t ws_size,
                              hipStream_t stream) {
    const float* x    = (const float*)d_in[0];
    const float* fcos = (const float*)d_in[1];
    const float* fsin = (const float*)d_in[2];
    const float* Wq = (const float*)d_in[4];
    const float* Wk = (const float*)d_in[5];
    const float* Wv = (const float*)d_in[6];
    const float* Wo = (const float*)d_in[7];
    const float* ln1 = (const float*)d_in[8];
    const float* ln2 = (const float*)d_in[9];
    const float* w1 = (const float*)d_in[10];
    const float* w2 = (const float*)d_in[11];
    const float* w3 = (const float*)d_in[12];
    float* out = (float*)d_out;

    char* ws = (char*)d_ws;
    size_t off = 0;
    auto alloc = [&](size_t bytes) -> char* {
        char* p = ws + off;
        off += (bytes + 255) & ~(size_t)255;
        return p;
    };
    u16* hb    = (u16*)alloc((size_t)S_LEN * D_MODEL * 2);
    u16* wqkvt = (u16*)alloc((size_t)QKV_LD * D_MODEL * 2);  // [3072][1024]
    u16* wot   = (u16*)alloc((size_t)D_MODEL * D_MODEL * 2);
    u16* qkvb  = (u16*)alloc((size_t)S_LEN * QKV_LD * 2);    // [4096][3072]
    u16* vt    = (u16*)alloc((size_t)S_LEN * D_MODEL * 2);   // [H][DK][S]
    u16* kpack = (u16*)alloc((size_t)S_LEN * D_MODEL * 2);   // [H][S][DK]
    u16* ctxb  = (u16*)alloc((size_t)S_LEN * D_MODEL * 2);
    float* x2  = (float*)alloc((size_t)S_LEN * D_MODEL * 4);
    u16* h2b   = (u16*)alloc((size_t)S_LEN * D_MODEL * 2);
    u16* w1t   = (u16*)alloc((size_t)HIDP * D_MODEL * 2);    // [2816][1024]
    u16* w3t   = (u16*)alloc((size_t)HIDP * D_MODEL * 2);
    u16* w2t   = (u16*)alloc((size_t)D_MODEL * HIDP * 2);    // [1024][2816]
    u16* ffb   = (u16*)alloc((size_t)S_LEN * HIDP * 2);      // [4096][2816]

    const dim3 tb32(32, 8);

    // all weight transposes in one launch
    tcast_all<<<12544, tb32, 0, stream>>>(
        Wq, Wk, Wv, Wo, w1, w3, w2,
        wqkvt, wqkvt + (size_t)D_MODEL * D_MODEL,
        wqkvt + (size_t)2 * D_MODEL * D_MODEL, wot, w1t, w3t, w2t);

    // h = rmsnorm(x, ln1)
    rmsnorm_k<<<S_LEN, 256, 0, stream>>>(x, ln1, hb);

    // QKV = h @ [Wq|Wk|Wv]   (one 4096x3072x1024 GEMM, raw Q/K)
    gemm128<0><<<dim3(QKV_LD / 128, S_LEN / 128), 256, 0, stream>>>(
        hb, D_MODEL, wqkvt, D_MODEL, qkvb, QKV_LD, D_MODEL, nullptr);

    // K packed (+RoPE) + V transposed per head
    packkv_k<<<dim3(S_LEN / 32, DK / 32, NHEAD), tb32, 0, stream>>>(
        qkvb, fcos, fsin, vt, kpack);

    // flash attention (Q RoPE fused; 128-kv tiles)
    flash_k<<<dim3(NHEAD, 64), 256, 0, stream>>>(qkvb, vt, kpack, fcos, fsin, ctxb);

    // x2 = x + ctx @ Wo
    gemm64r<<<dim3(D_MODEL / 64, S_LEN / 128), 256, 0, stream>>>(
        ctxb, D_MODEL, wot, D_MODEL, x2, D_MODEL, D_MODEL, x);

    // h2 = rmsnorm(x2, ln2)
    rmsnorm_k<<<S_LEN, 256, 0, stream>>>(x2, ln2, h2b);

    // ff = silu(h2@w1) * (h2@w3)
    gemm_dual64<<<dim3(HIDP / 64, S_LEN / 128), 256, 0, stream>>>(
        h2b, D_MODEL, w1t, w3t, D_MODEL, ffb, HIDP, D_MODEL);

    // out = x2 + ff @ w2
    gemm64r<<<dim3(D_MODEL / 64, S_LEN / 128), 256, 0, stream>>>(
        ffb, HIDP, w2t, HIDP, out, D_MODEL, HIDP, x2);
}

// Round 10
// 423.060 us; speedup vs baseline: 1.3327x; 1.0026x over previous
//
#include <hip/hip_runtime.h>

#define S_LEN 4096
#define D_MODEL 1024
#define NHEAD 16
#define DK 64
#define HID 2730
#define HIDP 2816
#define QKV_LD 3072

typedef unsigned short u16;
typedef unsigned int u32;
typedef __bf16 bf16x8 __attribute__((ext_vector_type(8)));
typedef float f32x4 __attribute__((ext_vector_type(4)));

#define MFMA16 __builtin_amdgcn_mfma_f32_16x16x32_bf16

__device__ __forceinline__ float b2f(u16 u) {
    return __builtin_bit_cast(float, (u32)u << 16);
}
__device__ __forceinline__ u16 f2b(float f) {
    u32 u = __builtin_bit_cast(u32, f);
    u += 0x7FFF + ((u >> 16) & 1);
    return (u16)(u >> 16);
}
// pack two f32 -> two bf16 (truncate) in one v_perm_b32
__device__ __forceinline__ u32 pk_trunc(float lo, float hi) {
    return __builtin_amdgcn_perm(__builtin_bit_cast(u32, hi),
                                 __builtin_bit_cast(u32, lo), 0x07060302u);
}
// async global->LDS, 16B per lane; dest must be wave-uniform base + lane*16
__device__ __forceinline__ void gll16(const u16* g, u16* l) {
    __builtin_amdgcn_global_load_lds(
        (__attribute__((address_space(1))) void*)(g),
        (__attribute__((address_space(3))) void*)(l),
        16, 0, 0);
}

// ---------------------------------------------------------------------------
// Prep: 7 weight transposes (fp32->bf16, zero-pad) + rmsnorm(x, ln1) in ONE
// launch. Flat grid, 256-thread blocks. Blocks 0..12543 = tcast segments;
// blocks 12544..16639 = rmsnorm rows.
// ---------------------------------------------------------------------------
__global__ __launch_bounds__(256)
void prep_k(const float* s0, const float* s1, const float* s2,
            const float* s3, const float* s4, const float* s5,
            const float* s6, u16* d0, u16* d1, u16* d2, u16* d3,
            u16* d4, u16* d5, u16* d6,
            const float* __restrict__ x, const float* __restrict__ ln1,
            u16* __restrict__ hb) {
    __shared__ float t[32][33];
    __shared__ float red[4];
    const int bid = blockIdx.x;
    const int tid = threadIdx.x;

    if (bid >= 12544) {   // ---- rmsnorm path ----
        const int row = bid - 12544;
        const float4 v = ((const float4*)(x + (size_t)row * D_MODEL))[tid];
        float ss = v.x * v.x + v.y * v.y + v.z * v.z + v.w * v.w;
        for (int o = 32; o; o >>= 1) ss += __shfl_down(ss, o);
        if ((tid & 63) == 0) red[tid >> 6] = ss;
        __syncthreads();
        const float tot = red[0] + red[1] + red[2] + red[3];
        const float rs = rsqrtf(tot * (1.0f / D_MODEL) + 1e-6f);
        const float4 wv = ((const float4*)ln1)[tid];
        u16* op = hb + (size_t)row * D_MODEL + tid * 4;
        u32 p0 = (u32)f2b(v.x * rs * wv.x) | ((u32)f2b(v.y * rs * wv.y) << 16);
        u32 p1 = (u32)f2b(v.z * rs * wv.z) | ((u32)f2b(v.w * rs * wv.w) << 16);
        uint2 pk; pk.x = p0; pk.y = p1;
        *(uint2*)op = pk;
        return;
    }

    // ---- transpose path ----
    const float* srcs[7] = {s0, s1, s2, s3, s4, s5, s6};
    u16* dsts[7] = {d0, d1, d2, d3, d4, d5, d6};
    const int RR[7] = {1024, 1024, 1024, 1024, 1024, 1024, 2730};
    const int CC[7] = {1024, 1024, 1024, 1024, 2730, 2730, 1024};
    const int OC[7] = {1024, 1024, 1024, 1024, 1024, 1024, 2816};
    const int XD[7] = {32, 32, 32, 32, 32, 32, 88};

    int seg, start;
    if (bid < 4096)      { seg = bid >> 10; start = seg << 10; }
    else if (bid < 6912) { seg = 4; start = 4096; }
    else if (bid < 9728) { seg = 5; start = 6912; }
    else                 { seg = 6; start = 9728; }
    const int local = bid - start;
    const int bx = local % XD[seg], byy = local / XD[seg];
    const float* in = srcs[seg];
    u16* out = dsts[seg];
    const int R = RR[seg], C = CC[seg], outC = OC[seg];

    const int r0 = byy * 32;
    const int c0 = bx * 32;
    const int tx = tid & 31, ty = tid >> 5;
#pragma unroll
    for (int j = 0; j < 4; ++j) {
        int ir = c0 + ty + j * 8;
        int ic = r0 + tx;
        t[ty + j * 8][tx] = (ir < R && ic < C) ? in[(size_t)ir * C + ic] : 0.0f;
    }
    __syncthreads();
#pragma unroll
    for (int j = 0; j < 4; ++j)
        out[(size_t)(r0 + ty + j * 8) * outC + c0 + tx] = f2b(t[tx][ty + j * 8]);
}

// ---------------------------------------------------------------------------
// RMSNorm (standalone, for x2 -> h2b)
// ---------------------------------------------------------------------------
__global__ __launch_bounds__(256)
void rmsnorm_k(const float* __restrict__ x, const float* __restrict__ w,
               u16* __restrict__ out) {
    const int row = blockIdx.x;
    const int tid = threadIdx.x;
    const float4 v = ((const float4*)(x + (size_t)row * D_MODEL))[tid];
    float ss = v.x * v.x + v.y * v.y + v.z * v.z + v.w * v.w;
    for (int o = 32; o; o >>= 1) ss += __shfl_down(ss, o);
    __shared__ float red[4];
    if ((tid & 63) == 0) red[tid >> 6] = ss;
    __syncthreads();
    const float tot = red[0] + red[1] + red[2] + red[3];
    const float rs = rsqrtf(tot * (1.0f / D_MODEL) + 1e-6f);
    const float4 wv = ((const float4*)w)[tid];
    u16* op = out + (size_t)row * D_MODEL + tid * 4;
    u32 p0 = (u32)f2b(v.x * rs * wv.x) | ((u32)f2b(v.y * rs * wv.y) << 16);
    u32 p1 = (u32)f2b(v.z * rs * wv.z) | ((u32)f2b(v.w * rs * wv.w) << 16);
    uint2 pk; pk.x = p0; pk.y = p1;
    *(uint2*)op = pk;
}

// ---------------------------------------------------------------------------
// Pack K/V per head, K-RoPE fused:
//   kp[h][s][d] = rope(qkv[s][1024 + h*64 + d])
//   vt[h][d][s] = qkv[s][2048 + h*64 + d]
// ---------------------------------------------------------------------------
__global__ __launch_bounds__(256)
void packkv_k(const u16* __restrict__ qkv, const float* __restrict__ fc,
              const float* __restrict__ fs, u16* __restrict__ vt,
              u16* __restrict__ kp) {
    __shared__ u16 t[32][33];
    const int h = blockIdx.z;
    const int t0 = blockIdx.x * 32;
    const int d0 = blockIdx.y * 32;
    const int tx = threadIdx.x, ty = threadIdx.y;
#pragma unroll
    for (int j = 0; j < 4; ++j)
        t[ty + j * 8][tx] =
            qkv[(size_t)(t0 + ty + j * 8) * QKV_LD + 2 * D_MODEL + h * DK + d0 + tx];

    const int id = ty * 32 + tx;
    const int sA = t0 + (id >> 3);
    const int dA = d0 + (id & 7) * 4;
    uint2 kvp = *(const uint2*)(qkv + (size_t)sA * QKV_LD + D_MODEL + h * DK + dA);
    const int fi = sA * 32 + (dA >> 1);
    const float cc0 = fc[fi], ss0 = fs[fi];
    const float cc1 = fc[fi + 1], ss1 = fs[fi + 1];
    auto rpk = [](u32 w, float c, float s) -> u32 {
        const float a = b2f((u16)w), b = b2f((u16)(w >> 16));
        return (u32)f2b(a * c - b * s) | ((u32)f2b(a * s + b * c) << 16);
    };
    kvp.x = rpk(kvp.x, cc0, ss0);
    kvp.y = rpk(kvp.y, cc1, ss1);
    *(uint2*)(kp + ((size_t)h * S_LEN + sA) * DK + dA) = kvp;

    __syncthreads();
#pragma unroll
    for (int j = 0; j < 4; ++j)
        vt[(size_t)h * DK * S_LEN + (size_t)(d0 + ty + j * 8) * S_LEN + t0 + tx] =
            t[tx][ty + j * 8];
}

// ---------------------------------------------------------------------------
// 128x128 GEMM (m97 structure): C = A @ Bt^T, global_load_lds staging.
// ---------------------------------------------------------------------------
template <int EPI>
__global__ __launch_bounds__(256)
void gemm128(const u16* __restrict__ A, int lda, const u16* __restrict__ Bt, int ldb,
             void* __restrict__ C, int ldc, int K, const float* __restrict__ resid) {
    const int m0 = blockIdx.y * 128, n0 = blockIdx.x * 128;
    const int tid = threadIdx.x;
    const int wave = tid >> 6, lane = tid & 63;
    const int wr = wave >> 1, wc = wave & 1;
    const int r16 = lane & 15, kq = lane >> 4;

    __shared__ __align__(16) u16 As[128 * 32];
    __shared__ __align__(16) u16 Bs[128 * 32];

    const int srow = tid >> 2, sk = (tid & 3) * 8;
    const u16* ag0 = A + (size_t)(m0 + srow) * lda + sk;
    const u16* ag1 = A + (size_t)(m0 + 64 + srow) * lda + sk;
    const u16* bg0 = Bt + (size_t)(n0 + srow) * ldb + sk;
    const u16* bg1 = Bt + (size_t)(n0 + 64 + srow) * ldb + sk;
    u16* asw = As + wave * 512;
    u16* bsw = Bs + wave * 512;

    f32x4 acc[16];
#pragma unroll
    for (int i = 0; i < 16; ++i) acc[i] = f32x4{0.f, 0.f, 0.f, 0.f};

    for (int k0 = 0; k0 < K; k0 += 32) {
        __syncthreads();
        gll16(ag0 + k0, asw);
        gll16(ag1 + k0, asw + 2048);
        gll16(bg0 + k0, bsw);
        gll16(bg1 + k0, bsw + 2048);
        __syncthreads();
        bf16x8 af[4], bf[4];
#pragma unroll
        for (int mt = 0; mt < 4; ++mt)
            af[mt] = *(const bf16x8*)&As[(wr * 64 + mt * 16 + r16) * 32 + kq * 8];
#pragma unroll
        for (int nt = 0; nt < 4; ++nt)
            bf[nt] = *(const bf16x8*)&Bs[(wc * 64 + nt * 16 + r16) * 32 + kq * 8];
#pragma unroll
        for (int mt = 0; mt < 4; ++mt)
#pragma unroll
            for (int nt = 0; nt < 4; ++nt)
                acc[mt * 4 + nt] = MFMA16(af[mt], bf[nt], acc[mt * 4 + nt], 0, 0, 0);
    }

#pragma unroll
    for (int mt = 0; mt < 4; ++mt) {
#pragma unroll
        for (int nt = 0; nt < 4; ++nt) {
            const int col = n0 + wc * 64 + nt * 16 + r16;
#pragma unroll
            for (int j = 0; j < 4; ++j) {
                const int row = m0 + wr * 64 + mt * 16 + kq * 4 + j;
                if (EPI == 0) {
                    ((u16*)C)[(size_t)row * ldc + col] = f2b(acc[mt * 4 + nt][j]);
                } else {
                    ((float*)C)[(size_t)row * ldc + col] =
                        resid[(size_t)row * ldc + col] + acc[mt * 4 + nt][j];
                }
            }
        }
    }
}

// ---------------------------------------------------------------------------
// 128(M) x 64(N) GEMM + fp32 residual epilogue (512 blocks at N=1024).
// ---------------------------------------------------------------------------
__global__ __launch_bounds__(256)
void gemm64r(const u16* __restrict__ A, int lda, const u16* __restrict__ Bt, int ldb,
             float* __restrict__ C, int ldc, int K, const float* __restrict__ resid) {
    const int m0 = blockIdx.y * 128, n0 = blockIdx.x * 64;
    const int tid = threadIdx.x;
    const int wave = tid >> 6, lane = tid & 63;
    const int r16 = lane & 15, kq = lane >> 4;

    __shared__ __align__(16) u16 As[128 * 32];
    __shared__ __align__(16) u16 Bs[64 * 32];

    const int srow = tid >> 2, sk = (tid & 3) * 8;
    const u16* ag0 = A + (size_t)(m0 + srow) * lda + sk;
    const u16* ag1 = A + (size_t)(m0 + 64 + srow) * lda + sk;
    const u16* bg = Bt + (size_t)(n0 + srow) * ldb + sk;
    u16* asw = As + wave * 512;
    u16* bsw = Bs + wave * 512;

    f32x4 acc[8];
#pragma unroll
    for (int i = 0; i < 8; ++i) acc[i] = f32x4{0.f, 0.f, 0.f, 0.f};

    for (int k0 = 0; k0 < K; k0 += 32) {
        __syncthreads();
        gll16(ag0 + k0, asw);
        gll16(ag1 + k0, asw + 2048);
        gll16(bg + k0, bsw);
        __syncthreads();
        bf16x8 af[2], bf[4];
#pragma unroll
        for (int mt = 0; mt < 2; ++mt)
            af[mt] = *(const bf16x8*)&As[(wave * 32 + mt * 16 + r16) * 32 + kq * 8];
#pragma unroll
        for (int nt = 0; nt < 4; ++nt)
            bf[nt] = *(const bf16x8*)&Bs[(nt * 16 + r16) * 32 + kq * 8];
#pragma unroll
        for (int mt = 0; mt < 2; ++mt)
#pragma unroll
            for (int nt = 0; nt < 4; ++nt)
                acc[mt * 4 + nt] = MFMA16(af[mt], bf[nt], acc[mt * 4 + nt], 0, 0, 0);
    }

#pragma unroll
    for (int mt = 0; mt < 2; ++mt)
#pragma unroll
        for (int nt = 0; nt < 4; ++nt) {
            const int col = n0 + nt * 16 + r16;
#pragma unroll
            for (int j = 0; j < 4; ++j) {
                const int row = m0 + wave * 32 + mt * 16 + kq * 4 + j;
                C[(size_t)row * ldc + col] =
                    resid[(size_t)row * ldc + col] + acc[mt * 4 + nt][j];
            }
        }
}

// ---------------------------------------------------------------------------
// FFN dual GEMM: tile 128(M) x 64(N per matrix); ff = silu(A@B1^T)*(A@B3^T)
// ---------------------------------------------------------------------------
__global__ __launch_bounds__(256)
void gemm_dual64(const u16* __restrict__ A, int lda,
                 const u16* __restrict__ B1, const u16* __restrict__ B3, int ldb,
                 u16* __restrict__ C, int ldc, int K) {
    const int m0 = blockIdx.y * 128, n0 = blockIdx.x * 64;
    const int tid = threadIdx.x;
    const int wave = tid >> 6, lane = tid & 63;
    const int r16 = lane & 15, kq = lane >> 4;

    __shared__ __align__(16) u16 As[128 * 32];
    __shared__ __align__(16) u16 B1s[64 * 32];
    __shared__ __align__(16) u16 B3s[64 * 32];

    const int srow = tid >> 2, sk = (tid & 3) * 8;
    const u16* ag0 = A + (size_t)(m0 + srow) * lda + sk;
    const u16* ag1 = A + (size_t)(m0 + 64 + srow) * lda + sk;
    const u16* b1g = B1 + (size_t)(n0 + srow) * ldb + sk;
    const u16* b3g = B3 + (size_t)(n0 + srow) * ldb + sk;
    u16* asw = As + wave * 512;
    u16* b1w = B1s + wave * 512;
    u16* b3w = B3s + wave * 512;

    f32x4 acc1[8], acc3[8];
#pragma unroll
    for (int i = 0; i < 8; ++i) {
        acc1[i] = f32x4{0.f, 0.f, 0.f, 0.f};
        acc3[i] = f32x4{0.f, 0.f, 0.f, 0.f};
    }

    for (int k0 = 0; k0 < K; k0 += 32) {
        __syncthreads();
        gll16(ag0 + k0, asw);
        gll16(ag1 + k0, asw + 2048);
        gll16(b1g + k0, b1w);
        gll16(b3g + k0, b3w);
        __syncthreads();
        bf16x8 af[2], b1f[4], b3f[4];
#pragma unroll
        for (int mt = 0; mt < 2; ++mt)
            af[mt] = *(const bf16x8*)&As[(wave * 32 + mt * 16 + r16) * 32 + kq * 8];
#pragma unroll
        for (int nt = 0; nt < 4; ++nt) {
            b1f[nt] = *(const bf16x8*)&B1s[(nt * 16 + r16) * 32 + kq * 8];
            b3f[nt] = *(const bf16x8*)&B3s[(nt * 16 + r16) * 32 + kq * 8];
        }
#pragma unroll
        for (int mt = 0; mt < 2; ++mt)
#pragma unroll
            for (int nt = 0; nt < 4; ++nt) {
                acc1[mt * 4 + nt] = MFMA16(af[mt], b1f[nt], acc1[mt * 4 + nt], 0, 0, 0);
                acc3[mt * 4 + nt] = MFMA16(af[mt], b3f[nt], acc3[mt * 4 + nt], 0, 0, 0);
            }
    }

#pragma unroll
    for (int mt = 0; mt < 2; ++mt)
#pragma unroll
        for (int nt = 0; nt < 4; ++nt) {
            const int col = n0 + nt * 16 + r16;
#pragma unroll
            for (int j = 0; j < 4; ++j) {
                const int row = m0 + wave * 32 + mt * 16 + kq * 4 + j;
                const float v1 = acc1[mt * 4 + nt][j];
                const float v3 = acc3[mt * 4 + nt][j];
                const float sig = 1.0f / (1.0f + __expf(-v1));
                C[(size_t)row * ldc + col] = f2b(v1 * sig * v3);
            }
        }
}

// ---------------------------------------------------------------------------
// Flash attention v6: 64-kv tiles, DOUBLE-BUFFERED LDS with async
// global_load_lds issued AFTER the (single) per-tile barrier -> next-tile
// loads overlap current-tile compute; drain at the next barrier is ~free
// (K/V L2-resident, compute > L2 latency). l computed on the MFMA pipe via
// ones-row MFMA over packed P (consistent with O; kills 16 VALU adds/tile
// and the end shuffles). LDS = 2*(8+8) + 8 = 40 KB -> 4 blocks/CU.
// ---------------------------------------------------------------------------
__global__ __launch_bounds__(256)
void flash_k(const u16* __restrict__ qkv, const u16* __restrict__ vt,
             const u16* __restrict__ kp, const float* __restrict__ fc,
             const float* __restrict__ fs, u16* __restrict__ ctx) {
    const int h = blockIdx.x;
    const int by = blockIdx.y;
    const int hi = by >> 4, lo = by & 15;
    const int base = lo + ((hi >> 1) << 4);
    const int qi = (hi & 1) ? (63 - base) : base;
    const int q0 = qi * 64;
    const int tid = threadIdx.x;
    const int wave = tid >> 6, lane = tid & 63;
    const int r16 = lane & 15, kq = lane >> 4;

    __shared__ __align__(16) u16 Kb[2][64 * 64];   // XOR-chunk-swizzled
    __shared__ __align__(16) u16 Vb[2][64 * 64];
    __shared__ __align__(16) u16 Ps[4 * 16 * 64];  // per-wave [q][kv], swizzled

    const u16* kb = kp + (size_t)h * S_LEN * DK;
    const u16* vb = vt + (size_t)h * DK * S_LEN;
    const int srow = tid >> 3;
    const int lcol = ((tid & 7) ^ (srow & 7)) * 8;
    const int qloc = wave * 16 + r16;
    const int qglob = q0 + qloc;
    const int sw = r16 & 7;
    const int c0 = (kq ^ sw) * 8;
    const int c1 = ((4 ^ kq) ^ sw) * 8;
    const int psw = r16 & 14;
    u16* psrow = Ps + wave * 1024 + r16 * 64;

    // Q: raw load + RoPE + 0.125*log2e scale, in registers
    const float SC = 0.125f * 1.44269504f;
    const u16* qrow = qkv + (size_t)qglob * QKV_LD + h * DK;
    uint4 uq0 = *(const uint4*)(qrow + kq * 8);
    uint4 uq1 = *(const uint4*)(qrow + 32 + kq * 8);
    const float4 c0v = *(const float4*)(fc + qglob * 32 + kq * 4);
    const float4 s0v = *(const float4*)(fs + qglob * 32 + kq * 4);
    const float4 c1v = *(const float4*)(fc + qglob * 32 + 16 + kq * 4);
    const float4 s1v = *(const float4*)(fs + qglob * 32 + 16 + kq * 4);
    auto rp = [SC](u32 w, float c, float s) -> u32 {
        const float a = b2f((u16)w), b = b2f((u16)(w >> 16));
        return (u32)f2b((a * c - b * s) * SC) |
               ((u32)f2b((a * s + b * c) * SC) << 16);
    };
    uq0.x = rp(uq0.x, c0v.x, s0v.x); uq0.y = rp(uq0.y, c0v.y, s0v.y);
    uq0.z = rp(uq0.z, c0v.z, s0v.z); uq0.w = rp(uq0.w, c0v.w, s0v.w);
    uq1.x = rp(uq1.x, c1v.x, s1v.x); uq1.y = rp(uq1.y, c1v.y, s1v.y);
    uq1.z = rp(uq1.z, c1v.z, s1v.z); uq1.w = rp(uq1.w, c1v.w, s1v.w);
    const bf16x8 qf0 = __builtin_bit_cast(bf16x8, uq0);
    const bf16x8 qf1 = __builtin_bit_cast(bf16x8, uq1);

    f32x4 o[4];
#pragma unroll
    for (int i = 0; i < 4; ++i) o[i] = f32x4{0.f, 0.f, 0.f, 0.f};
    f32x4 lacc = f32x4{0.f, 0.f, 0.f, 0.f};
    const uint4 uone = make_uint4(0x3F803F80u, 0x3F803F80u, 0x3F803F80u, 0x3F803F80u);
    const bf16x8 ones = __builtin_bit_cast(bf16x8, uone);

    // preload tile 0 into buffer 0
#pragma unroll
    for (int i = 0; i < 2; ++i) {
        const int r = srow + i * 32;
        gll16(kb + (size_t)r * DK + lcol, Kb[0] + tid * 8 + i * 2048);
        gll16(vb + (size_t)r * S_LEN + lcol, Vb[0] + tid * 8 + i * 2048);
    }

    for (int t = 0; t <= qi; ++t) {
        __syncthreads();   // drains tile-t loads; all waves done with buf[(t+1)&1]
        if (t < qi) {      // issue next-tile loads NOW; they overlap compute below
            const int t1 = (t + 1) * 64;
            u16* kd = Kb[(t + 1) & 1];
            u16* vd = Vb[(t + 1) & 1];
#pragma unroll
            for (int i = 0; i < 2; ++i) {
                const int r = srow + i * 32;
                gll16(kb + (size_t)(t1 + r) * DK + lcol, kd + tid * 8 + i * 2048);
                gll16(vb + (size_t)r * S_LEN + t1 + lcol, vd + tid * 8 + i * 2048);
            }
        }
        const u16* Ks = Kb[t & 1];
        const u16* Vs = Vb[t & 1];

        // S^T[kv][q] = K·Q^T: col=q=r16 per lane
        f32x4 s[4];
#pragma unroll
        for (int nt = 0; nt < 4; ++nt) {
            s[nt] = f32x4{0.f, 0.f, 0.f, 0.f};
            const bf16x8 k0 = *(const bf16x8*)&Ks[(nt * 16 + r16) * 64 + c0];
            s[nt] = MFMA16(k0, qf0, s[nt], 0, 0, 0);
            const bf16x8 k1 = *(const bf16x8*)&Ks[(nt * 16 + r16) * 64 + c1];
            s[nt] = MFMA16(k1, qf1, s[nt], 0, 0, 0);
        }

        // p = 2^s, diag-masked to 0 on the last tile
        float pr[16];
#pragma unroll
        for (int nt = 0; nt < 4; ++nt)
#pragma unroll
            for (int j = 0; j < 4; ++j) pr[nt * 4 + j] = exp2f(s[nt][j]);
        if (t == qi) {
#pragma unroll
            for (int nt = 0; nt < 4; ++nt)
#pragma unroll
                for (int j = 0; j < 4; ++j)
                    if ((nt * 16 + kq * 4 + j) > qloc) pr[nt * 4 + j] = 0.f;
        }

        // P^T -> swizzled wave-private Ps [q=r16][kv]
#pragma unroll
        for (int nt = 0; nt < 4; ++nt) {
            uint2 pk;
            pk.x = pk_trunc(pr[nt * 4 + 0], pr[nt * 4 + 1]);
            pk.y = pk_trunc(pr[nt * 4 + 2], pr[nt * 4 + 3]);
            *(uint2*)&psrow[((nt * 4 + kq) ^ psw) * 4] = pk;
        }

        // O^T += V^T @ P^T ; l += ones @ P^T (MFMA pipe, consistent with O)
#pragma unroll
        for (int ks = 0; ks < 2; ++ks) {
            const bf16x8 pf = *(const bf16x8*)&psrow[((8 * ks + 2 * kq) ^ psw) * 4];
            lacc = MFMA16(ones, pf, lacc, 0, 0, 0);
            const int cv = (((ks << 2) ^ kq) ^ sw) * 8;
#pragma unroll
            for (int nt = 0; nt < 4; ++nt) {
                const bf16x8 vf = *(const bf16x8*)&Vs[(nt * 16 + r16) * 64 + cv];
                o[nt] = MFMA16(vf, pf, o[nt], 0, 0, 0);
            }
        }
    }

    // l: every lacc element equals the full sum for column q=r16
    const float inv = 1.0f / lacc[0];
    const size_t row = qglob;
#pragma unroll
    for (int nt = 0; nt < 4; ++nt) {
        uint2 pk;
        pk.x = (u32)f2b(o[nt][0] * inv) | ((u32)f2b(o[nt][1] * inv) << 16);
        pk.y = (u32)f2b(o[nt][2] * inv) | ((u32)f2b(o[nt][3] * inv) << 16);
        *(uint2*)&ctx[row * D_MODEL + h * DK + nt * 16 + kq * 4] = pk;
    }
}

// ---------------------------------------------------------------------------
extern "C" void kernel_launch(void* const* d_in, const int* in_sizes, int n_in,
                              void* d_out, int out_size, void* d_ws, size_t ws_size,
                              hipStream_t stream) {
    const float* x    = (const float*)d_in[0];
    const float* fcos = (const float*)d_in[1];
    const float* fsin = (const float*)d_in[2];
    const float* Wq = (const float*)d_in[4];
    const float* Wk = (const float*)d_in[5];
    const float* Wv = (const float*)d_in[6];
    const float* Wo = (const float*)d_in[7];
    const float* ln1 = (const float*)d_in[8];
    const float* ln2 = (const float*)d_in[9];
    const float* w1 = (const float*)d_in[10];
    const float* w2 = (const float*)d_in[11];
    const float* w3 = (const float*)d_in[12];
    float* out = (float*)d_out;

    char* ws = (char*)d_ws;
    size_t off = 0;
    auto alloc = [&](size_t bytes) -> char* {
        char* p = ws + off;
        off += (bytes + 255) & ~(size_t)255;
        return p;
    };
    u16* hb    = (u16*)alloc((size_t)S_LEN * D_MODEL * 2);
    u16* wqkvt = (u16*)alloc((size_t)QKV_LD * D_MODEL * 2);  // [3072][1024]
    u16* wot   = (u16*)alloc((size_t)D_MODEL * D_MODEL * 2);
    u16* qkvb  = (u16*)alloc((size_t)S_LEN * QKV_LD * 2);    // [4096][3072]
    u16* vt    = (u16*)alloc((size_t)S_LEN * D_MODEL * 2);   // [H][DK][S]
    u16* kpack = (u16*)alloc((size_t)S_LEN * D_MODEL * 2);   // [H][S][DK]
    u16* ctxb  = (u16*)alloc((size_t)S_LEN * D_MODEL * 2);
    float* x2  = (float*)alloc((size_t)S_LEN * D_MODEL * 4);
    u16* h2b   = (u16*)alloc((size_t)S_LEN * D_MODEL * 2);
    u16* w1t   = (u16*)alloc((size_t)HIDP * D_MODEL * 2);    // [2816][1024]
    u16* w3t   = (u16*)alloc((size_t)HIDP * D_MODEL * 2);
    u16* w2t   = (u16*)alloc((size_t)D_MODEL * HIDP * 2);    // [1024][2816]
    u16* ffb   = (u16*)alloc((size_t)S_LEN * HIDP * 2);      // [4096][2816]

    const dim3 tb32(32, 8);

    // weight transposes + rmsnorm(x, ln1), one launch
    prep_k<<<16640, 256, 0, stream>>>(
        Wq, Wk, Wv, Wo, w1, w3, w2,
        wqkvt, wqkvt + (size_t)D_MODEL * D_MODEL,
        wqkvt + (size_t)2 * D_MODEL * D_MODEL, wot, w1t, w3t, w2t,
        x, ln1, hb);

    // QKV = h @ [Wq|Wk|Wv]   (one 4096x3072x1024 GEMM, raw Q/K)
    gemm128<0><<<dim3(QKV_LD / 128, S_LEN / 128), 256, 0, stream>>>(
        hb, D_MODEL, wqkvt, D_MODEL, qkvb, QKV_LD, D_MODEL, nullptr);

    // K packed (+RoPE) + V transposed per head
    packkv_k<<<dim3(S_LEN / 32, DK / 32, NHEAD), tb32, 0, stream>>>(
        qkvb, fcos, fsin, vt, kpack);

    // flash attention (Q RoPE fused; double-buffered 64-kv tiles)
    flash_k<<<dim3(NHEAD, 64), 256, 0, stream>>>(qkvb, vt, kpack, fcos, fsin, ctxb);

    // x2 = x + ctx @ Wo
    gemm64r<<<dim3(D_MODEL / 64, S_LEN / 128), 256, 0, stream>>>(
        ctxb, D_MODEL, wot, D_MODEL, x2, D_MODEL, D_MODEL, x);

    // h2 = rmsnorm(x2, ln2)
    rmsnorm_k<<<S_LEN, 256, 0, stream>>>(x2, ln2, h2b);

    // ff = silu(h2@w1) * (h2@w3)
    gemm_dual64<<<dim3(HIDP / 64, S_LEN / 128), 256, 0, stream>>>(
        h2b, D_MODEL, w1t, w3t, D_MODEL, ffb, HIDP, D_MODEL);

    // out = x2 + ff @ w2
    gemm64r<<<dim3(D_MODEL / 64, S_LEN / 128), 256, 0, stream>>>(
        ffb, HIDP, w2t, HIDP, out, D_MODEL, HIDP, x2);
}